// Round 1
// baseline (978.656 us; speedup 1.0000x reference)
//
#include <hip/hip_runtime.h>

#define N_NODES 50000
#define N_EDGES 800000
#define NGRAPH 64

// ---------------------------------------------------------------------------
// 1) edge histogram: weighted degree (float) + edge count per dst (int)
__global__ __launch_bounds__(256) void edge_hist_kernel(
    const int* __restrict__ ei1, const float* __restrict__ w1,
    const int* __restrict__ ei2, const float* __restrict__ w2,
    float* __restrict__ deg1, float* __restrict__ deg2,
    int* __restrict__ hist1, int* __restrict__ hist2) {
  int e = blockIdx.x * 256 + threadIdx.x;
  if (e >= N_EDGES) return;
  int d1 = ei1[N_EDGES + e];
  atomicAdd(&deg1[d1], w1[e]);
  atomicAdd(&hist1[d1], 1);
  int d2 = ei2[N_EDGES + e];
  atomicAdd(&deg2[d2], w2[e]);
  atomicAdd(&hist2[d2], 1);
}

// 2) dis = rsqrt(deg + 1)   (self-loop weight 1 added here; deg+1 >= 1 always)
__global__ __launch_bounds__(256) void dis_kernel(float* deg1, float* deg2) {
  int i = blockIdx.x * 256 + threadIdx.x;
  if (i >= N_NODES) return;
  deg1[i] = rsqrtf(deg1[i] + 1.0f);
  deg2[i] = rsqrtf(deg2[i] + 1.0f);
}

// 3) exclusive scan of hist -> rowptr & cursor.  2 blocks (one per graph).
__global__ __launch_bounds__(1024) void scan_kernel(
    const int* __restrict__ h1, const int* __restrict__ h2,
    int* __restrict__ rp1, int* __restrict__ rp2,
    int* __restrict__ cur1, int* __restrict__ cur2) {
  const int* hist = blockIdx.x ? h2 : h1;
  int* rowptr = blockIdx.x ? rp2 : rp1;
  int* cursor = blockIdx.x ? cur2 : cur1;
  __shared__ int wsums[16];
  __shared__ int s_carry;
  int tid = threadIdx.x, lane = tid & 63, wid = tid >> 6;
  if (tid == 0) s_carry = 0;
  for (int base = 0; base < N_NODES; base += 1024) {
    __syncthreads();  // protects wsums/s_carry from previous iteration
    int i = base + tid;
    int v = (i < N_NODES) ? hist[i] : 0;
    int incl = v;
#pragma unroll
    for (int off = 1; off < 64; off <<= 1) {
      int t = __shfl_up(incl, off, 64);
      if (lane >= off) incl += t;
    }
    if (lane == 63) wsums[wid] = incl;
    __syncthreads();
    if (wid == 0) {
      int wv = (lane < 16) ? wsums[lane] : 0;
      int wincl = wv;
#pragma unroll
      for (int off = 1; off < 16; off <<= 1) {
        int t = __shfl_up(wincl, off, 64);
        if (lane >= off) wincl += t;
      }
      if (lane < 16) wsums[lane] = wincl - wv;  // exclusive wave offsets
    }
    __syncthreads();
    int excl = s_carry + wsums[wid] + (incl - v);
    if (i < N_NODES) { rowptr[i] = excl; cursor[i] = excl; }
    __syncthreads();
    if (tid == 1023) s_carry += wsums[15] + incl;  // chunk total
  }
  __syncthreads();
  if (tid == 1023) rowptr[N_NODES] = s_carry;
}

// 4) CSR fill; coef = w * dis[src] precomputed
__global__ __launch_bounds__(256) void fill_kernel(
    const int* __restrict__ ei1, const float* __restrict__ w1,
    const float* __restrict__ dis1, int* __restrict__ cur1,
    int* __restrict__ csrc1, float* __restrict__ coef1,
    const int* __restrict__ ei2, const float* __restrict__ w2,
    const float* __restrict__ dis2, int* __restrict__ cur2,
    int* __restrict__ csrc2, float* __restrict__ coef2) {
  int e = blockIdx.x * 256 + threadIdx.x;
  if (e >= N_EDGES) return;
  {
    int s = ei1[e], d = ei1[N_EDGES + e];
    int slot = atomicAdd(&cur1[d], 1);
    csrc1[slot] = s;
    coef1[slot] = w1[e] * dis1[s];
  }
  {
    int s = ei2[e], d = ei2[N_EDGES + e];
    int slot = atomicAdd(&cur2[d], 1);
    csrc2[slot] = s;
    coef2[slot] = w2[e] * dis2[s];
  }
}

// 5) GEMM: Y[r] = Xsel[r] @ W  for r in [0, 2N).  Row < N reads X0, else X1.
//    Block: 256 thr, tile 128 rows x 128 cols, full K=128.
//    Lanes <-> rows (ds_read_b64 from XOR-swizzled transposed LDS tile);
//    W wave-uniform (readfirstlane) -> scalar loads, FMA-bound.
__global__ __launch_bounds__(256, 2) void gemm_kernel(
    const float* __restrict__ X0, const float* __restrict__ X1,
    const float* __restrict__ W, float* __restrict__ Y) {
  __shared__ float xsT[128 * 128];
  const int tid = threadIdx.x;
  const int rbase = blockIdx.x * 128;
  // stage transposed with XOR swizzle: addr(k,row) = k*128 + (row ^ (k & 28))
#pragma unroll
  for (int it = 0; it < 16; ++it) {
    int idx = it * 256 + tid;
    int row = idx >> 5;   // 0..127
    int k4 = idx & 31;    // float4 index along k
    int gr = rbase + row;
    float4 v = make_float4(0.f, 0.f, 0.f, 0.f);
    if (gr < 2 * N_NODES) {
      const float* src = (gr < N_NODES) ? (X0 + (size_t)gr * 128)
                                        : (X1 + (size_t)(gr - N_NODES) * 128);
      v = ((const float4*)src)[k4];
    }
    int k0 = k4 * 4;
    xsT[(k0 + 0) * 128 + (row ^ ((k0 + 0) & 28))] = v.x;
    xsT[(k0 + 1) * 128 + (row ^ ((k0 + 1) & 28))] = v.y;
    xsT[(k0 + 2) * 128 + (row ^ ((k0 + 2) & 28))] = v.z;
    xsT[(k0 + 3) * 128 + (row ^ ((k0 + 3) & 28))] = v.w;
  }
  __syncthreads();
  const int wv = __builtin_amdgcn_readfirstlane(tid >> 6);  // wave id 0..3
  const int c0 = wv * 32;                                   // wave-uniform col base
  const int lane = tid & 63;
  const int r2 = lane * 2;
  float acc0[32], acc1[32];
#pragma unroll
  for (int u = 0; u < 32; ++u) { acc0[u] = 0.f; acc1[u] = 0.f; }
  for (int k = 0; k < 128; ++k) {
    const float2 x = *(const float2*)&xsT[k * 128 + (r2 ^ (k & 28))];
    const float* __restrict__ wr = W + k * 128 + c0;  // uniform -> s_load
#pragma unroll
    for (int u = 0; u < 32; ++u) {
      float wval = wr[u];
      acc0[u] += x.x * wval;
      acc1[u] += x.y * wval;
    }
  }
  int gr0 = rbase + r2;
  if (gr0 < 2 * N_NODES) {
    float4* dst = (float4*)(Y + (size_t)gr0 * 128 + c0);
#pragma unroll
    for (int u = 0; u < 8; ++u)
      dst[u] = make_float4(acc0[4 * u], acc0[4 * u + 1], acc0[4 * u + 2], acc0[4 * u + 3]);
  }
  if (gr0 + 1 < 2 * N_NODES) {
    float4* dst = (float4*)(Y + (size_t)(gr0 + 1) * 128 + c0);
#pragma unroll
    for (int u = 0; u < 8; ++u)
      dst[u] = make_float4(acc1[4 * u], acc1[4 * u + 1], acc1[4 * u + 2], acc1[4 * u + 3]);
  }
}

// 6) layer-1 aggregate: out[i] = b + dis[i]^2 * H[i] + dis[i] * sum coef_e * H[src_e]
//    idx in [0,2N): graph1 nodes then graph2 nodes.  128 threads per node.
__global__ __launch_bounds__(256) void aggregate1_kernel(
    const int* __restrict__ rp1, const int* __restrict__ cs1,
    const float* __restrict__ cf1, const float* __restrict__ dis1,
    const int* __restrict__ rp2, const int* __restrict__ cs2,
    const float* __restrict__ cf2, const float* __restrict__ dis2,
    const float* __restrict__ H, const float* __restrict__ bias,
    float* __restrict__ out) {
  int idx = blockIdx.x * 2 + (threadIdx.x >> 7);
  int j = threadIdx.x & 127;
  const int *rp, *cs;
  const float *cf, *dis, *Hb;
  int node;
  if (idx < N_NODES) {
    rp = rp1; cs = cs1; cf = cf1; dis = dis1; node = idx; Hb = H;
  } else {
    rp = rp2; cs = cs2; cf = cf2; dis = dis2; node = idx - N_NODES;
    Hb = H + (size_t)N_NODES * 128;
  }
  int beg = rp[node], end = rp[node + 1];
  float acc = 0.f;
  for (int e = beg; e < end; ++e) {
    acc += cf[e] * Hb[(size_t)cs[e] * 128 + j];
  }
  float di = dis[node];
  out[(size_t)idx * 128 + j] =
      bias[j] + di * di * Hb[(size_t)node * 128 + j] + di * acc;
}

// 7) fused layer-2 aggregate (both graphs) + diff-product + chunked mean-pool
//    accumulate.  128 threads (thread j = feature j), CHUNK=16 nodes per block.
__global__ __launch_bounds__(128) void aggregate2_pool_kernel(
    const int* __restrict__ rp1, const int* __restrict__ cs1,
    const float* __restrict__ cf1, const float* __restrict__ dis1,
    const int* __restrict__ rp2, const int* __restrict__ cs2,
    const float* __restrict__ cf2, const float* __restrict__ dis2,
    const float* __restrict__ T,   // t1 at 0, t2 at N*128
    const float* __restrict__ X1,  // x11 at 0, x12 at N*128
    const float* __restrict__ b2, const int* __restrict__ batch,
    float* __restrict__ pool) {
  const int j = threadIdx.x;  // 0..127
  const int base = blockIdx.x * 16;
  const float bj = b2[j];
  const size_t off2 = (size_t)N_NODES * 128;
  float acc = 0.f;
  int curg = -1;
  for (int t = 0; t < 16; ++t) {
    int i = base + t;
    if (i >= N_NODES) break;
    float a1 = 0.f;
    int e1 = rp1[i], e1e = rp1[i + 1];
    for (int e = e1; e < e1e; ++e) a1 += cf1[e] * T[(size_t)cs1[e] * 128 + j];
    float d1 = dis1[i];
    float x21 = bj + d1 * d1 * T[(size_t)i * 128 + j] + d1 * a1;
    float a2 = 0.f;
    int e2 = rp2[i], e2e = rp2[i + 1];
    for (int e = e2; e < e2e; ++e) a2 += cf2[e] * T[off2 + (size_t)cs2[e] * 128 + j];
    float d2 = dis2[i];
    float x22 = bj + d2 * d2 * T[off2 + (size_t)i * 128 + j] + d2 * a2;
    float v = (X1[off2 + (size_t)i * 128 + j] - X1[(size_t)i * 128 + j]) * (x22 - x21);
    int g = batch[i];
    if (g != curg) {
      if (curg >= 0) atomicAdd(&pool[curg * 128 + j], acc);
      acc = 0.f;
      curg = g;
    }
    acc += v;
  }
  if (curg >= 0) atomicAdd(&pool[curg * 128 + j], acc);
}

// 8) per-graph mean + 4-layer MLP.  One block per graph, 128 threads.
__global__ __launch_bounds__(128) void mlp_kernel(
    const float* __restrict__ pool, const int* __restrict__ batch,
    const float* __restrict__ M1w, const float* __restrict__ M1b,
    const float* __restrict__ M2w, const float* __restrict__ M2b,
    const float* __restrict__ M3w, const float* __restrict__ M3b,
    const float* __restrict__ M4w, const float* __restrict__ M4b,
    float* __restrict__ out) {
  __shared__ float gv[128], t1[128], t2[64], t3[32];
  const int g = blockIdx.x, j = threadIdx.x;
  // node count for graph g via binary search on sorted batch
  int lo, hi;
  { int a = 0, b = N_NODES; while (a < b) { int m = (a + b) >> 1; if (batch[m] < g) a = m + 1; else b = m; } lo = a; }
  { int a = lo, b = N_NODES; while (a < b) { int m = (a + b) >> 1; if (batch[m] < g + 1) a = m + 1; else b = m; } hi = a; }
  float cnt = (float)(hi - lo);
  if (cnt < 1.f) cnt = 1.f;
  gv[j] = pool[g * 128 + j] / cnt;
  __syncthreads();
  float a = M1b[j];
  for (int k = 0; k < 128; ++k) a += gv[k] * M1w[k * 128 + j];
  t1[j] = a;
  __syncthreads();
  if (j < 64) {
    float b = M2b[j];
    for (int k = 0; k < 128; ++k) b += t1[k] * M2w[k * 64 + j];
    t2[j] = b;
  }
  __syncthreads();
  if (j < 32) {
    float c = M3b[j];
    for (int k = 0; k < 64; ++k) c += t2[k] * M3w[k * 32 + j];
    t3[j] = c;
  }
  __syncthreads();
  if (j == 0) {
    float o = M4b[0];
    for (int k = 0; k < 32; ++k) o += t3[k] * M4w[k];
    out[g] = o;
  }
}

// ---------------------------------------------------------------------------
extern "C" void kernel_launch(void* const* d_in, const int* in_sizes, int n_in,
                              void* d_out, int out_size, void* d_ws, size_t ws_size,
                              hipStream_t stream) {
  const int* ei1 = (const int*)d_in[0];
  const float* w1 = (const float*)d_in[1];
  const int* ei2 = (const int*)d_in[2];
  const float* w2 = (const float*)d_in[3];
  const float* fm0 = (const float*)d_in[4];
  const float* fm1 = (const float*)d_in[5];
  const int* batch = (const int*)d_in[6];
  const float* W1 = (const float*)d_in[7];
  const float* b1 = (const float*)d_in[8];
  const float* W2 = (const float*)d_in[9];
  const float* b2 = (const float*)d_in[10];
  const float* M1w = (const float*)d_in[11];
  const float* M1b = (const float*)d_in[12];
  const float* M2w = (const float*)d_in[13];
  const float* M2b = (const float*)d_in[14];
  const float* M3w = (const float*)d_in[15];
  const float* M3b = (const float*)d_in[16];
  const float* M4w = (const float*)d_in[17];
  const float* M4b = (const float*)d_in[18];

  // workspace layout (element offsets, 16-element aligned)
  size_t off = 0;
  auto alloc = [&](size_t n) { size_t r = off; off += (n + 15) & ~(size_t)15; return r; };
  size_t o_deg1 = alloc(N_NODES);
  size_t o_deg2 = alloc(N_NODES);
  size_t o_hist1 = alloc(N_NODES);
  size_t o_hist2 = alloc(N_NODES);
  size_t o_pool = alloc(NGRAPH * 128);
  size_t zero_elems = off;  // everything above gets zeroed
  size_t o_rp1 = alloc(N_NODES + 1);
  size_t o_rp2 = alloc(N_NODES + 1);
  size_t o_cur1 = alloc(N_NODES);
  size_t o_cur2 = alloc(N_NODES);
  size_t o_cs1 = alloc(N_EDGES);
  size_t o_cs2 = alloc(N_EDGES);
  size_t o_cf1 = alloc(N_EDGES);
  size_t o_cf2 = alloc(N_EDGES);
  size_t o_h = alloc((size_t)2 * N_NODES * 128);
  size_t o_x1 = alloc((size_t)2 * N_NODES * 128);
  if (ws_size < off * sizeof(float)) return;  // insufficient workspace: fail loudly

  float* fbase = (float*)d_ws;
  int* ibase = (int*)d_ws;
  float* deg1 = fbase + o_deg1;
  float* deg2 = fbase + o_deg2;
  int* hist1 = ibase + o_hist1;
  int* hist2 = ibase + o_hist2;
  float* pool = fbase + o_pool;
  int* rp1 = ibase + o_rp1;
  int* rp2 = ibase + o_rp2;
  int* cur1 = ibase + o_cur1;
  int* cur2 = ibase + o_cur2;
  int* cs1 = ibase + o_cs1;
  int* cs2 = ibase + o_cs2;
  float* cf1 = fbase + o_cf1;
  float* cf2 = fbase + o_cf2;
  float* h = fbase + o_h;
  float* x1 = fbase + o_x1;

  hipMemsetAsync(d_ws, 0, zero_elems * sizeof(float), stream);

  edge_hist_kernel<<<(N_EDGES + 255) / 256, 256, 0, stream>>>(
      ei1, w1, ei2, w2, deg1, deg2, hist1, hist2);
  dis_kernel<<<(N_NODES + 255) / 256, 256, 0, stream>>>(deg1, deg2);
  scan_kernel<<<2, 1024, 0, stream>>>(hist1, hist2, rp1, rp2, cur1, cur2);
  fill_kernel<<<(N_EDGES + 255) / 256, 256, 0, stream>>>(
      ei1, w1, deg1, cur1, cs1, cf1, ei2, w2, deg2, cur2, cs2, cf2);
  // layer 1: h = [fm0; fm1] @ W1
  gemm_kernel<<<(2 * N_NODES + 127) / 128, 256, 0, stream>>>(fm0, fm1, W1, h);
  aggregate1_kernel<<<N_NODES, 256, 0, stream>>>(
      rp1, cs1, cf1, deg1, rp2, cs2, cf2, deg2, h, b1, x1);
  // layer 2: t = [x11; x12] @ W2 (overwrites h)
  gemm_kernel<<<(2 * N_NODES + 127) / 128, 256, 0, stream>>>(
      x1, x1 + (size_t)N_NODES * 128, W2, h);
  aggregate2_pool_kernel<<<(N_NODES + 15) / 16, 128, 0, stream>>>(
      rp1, cs1, cf1, deg1, rp2, cs2, cf2, deg2, h, x1, b2, batch, pool);
  mlp_kernel<<<NGRAPH, 128, 0, stream>>>(
      pool, batch, M1w, M1b, M2w, M2b, M3w, M3b, M4w, M4b, (float*)d_out);
}

// Round 2
// 801.122 us; speedup vs baseline: 1.2216x; 1.2216x over previous
//
#include <hip/hip_runtime.h>

#define N_NODES 50000
#define N_EDGES 800000
#define NGRAPH 64

// ---------------------------------------------------------------------------
// unrolled gather: 4 independent accumulators -> 4 row-gathers in flight
__device__ __forceinline__ float edge_gather(
    const int* __restrict__ cs, const float* __restrict__ cf,
    int beg, int end, const float* __restrict__ Hb, int j) {
  float a0 = 0.f, a1 = 0.f, a2 = 0.f, a3 = 0.f;
  int e = beg;
  for (; e + 4 <= end; e += 4) {
    int s0 = cs[e], s1 = cs[e + 1], s2 = cs[e + 2], s3 = cs[e + 3];
    float c0 = cf[e], c1 = cf[e + 1], c2 = cf[e + 2], c3 = cf[e + 3];
    a0 += c0 * Hb[(size_t)s0 * 128 + j];
    a1 += c1 * Hb[(size_t)s1 * 128 + j];
    a2 += c2 * Hb[(size_t)s2 * 128 + j];
    a3 += c3 * Hb[(size_t)s3 * 128 + j];
  }
  for (; e < end; ++e) a0 += cf[e] * Hb[(size_t)cs[e] * 128 + j];
  return (a0 + a1) + (a2 + a3);
}

// ---------------------------------------------------------------------------
// 1) edge histogram: weighted degree (float) + edge count per dst (int)
__global__ __launch_bounds__(256) void edge_hist_kernel(
    const int* __restrict__ ei1, const float* __restrict__ w1,
    const int* __restrict__ ei2, const float* __restrict__ w2,
    float* __restrict__ deg1, float* __restrict__ deg2,
    int* __restrict__ hist1, int* __restrict__ hist2) {
  int e = blockIdx.x * 256 + threadIdx.x;
  if (e >= N_EDGES) return;
  int d1 = ei1[N_EDGES + e];
  atomicAdd(&deg1[d1], w1[e]);
  atomicAdd(&hist1[d1], 1);
  int d2 = ei2[N_EDGES + e];
  atomicAdd(&deg2[d2], w2[e]);
  atomicAdd(&hist2[d2], 1);
}

// 2) dis = rsqrt(deg + 1)   (self-loop weight 1 added here; deg+1 >= 1 always)
__global__ __launch_bounds__(256) void dis_kernel(float* deg1, float* deg2) {
  int i = blockIdx.x * 256 + threadIdx.x;
  if (i >= N_NODES) return;
  deg1[i] = rsqrtf(deg1[i] + 1.0f);
  deg2[i] = rsqrtf(deg2[i] + 1.0f);
}

// 3) exclusive scan of hist -> rowptr & cursor.  2 blocks (one per graph).
__global__ __launch_bounds__(1024) void scan_kernel(
    const int* __restrict__ h1, const int* __restrict__ h2,
    int* __restrict__ rp1, int* __restrict__ rp2,
    int* __restrict__ cur1, int* __restrict__ cur2) {
  const int* hist = blockIdx.x ? h2 : h1;
  int* rowptr = blockIdx.x ? rp2 : rp1;
  int* cursor = blockIdx.x ? cur2 : cur1;
  __shared__ int wsums[16];
  __shared__ int s_carry;
  int tid = threadIdx.x, lane = tid & 63, wid = tid >> 6;
  if (tid == 0) s_carry = 0;
  for (int base = 0; base < N_NODES; base += 1024) {
    __syncthreads();  // protects wsums/s_carry from previous iteration
    int i = base + tid;
    int v = (i < N_NODES) ? hist[i] : 0;
    int incl = v;
#pragma unroll
    for (int off = 1; off < 64; off <<= 1) {
      int t = __shfl_up(incl, off, 64);
      if (lane >= off) incl += t;
    }
    if (lane == 63) wsums[wid] = incl;
    __syncthreads();
    if (wid == 0) {
      int wv = (lane < 16) ? wsums[lane] : 0;
      int wincl = wv;
#pragma unroll
      for (int off = 1; off < 16; off <<= 1) {
        int t = __shfl_up(wincl, off, 64);
        if (lane >= off) wincl += t;
      }
      if (lane < 16) wsums[lane] = wincl - wv;  // exclusive wave offsets
    }
    __syncthreads();
    int excl = s_carry + wsums[wid] + (incl - v);
    if (i < N_NODES) { rowptr[i] = excl; cursor[i] = excl; }
    __syncthreads();
    if (tid == 1023) s_carry += wsums[15] + incl;  // chunk total
  }
  __syncthreads();
  if (tid == 1023) rowptr[N_NODES] = s_carry;
}

// 4) CSR fill; coef = w * dis[src] precomputed
__global__ __launch_bounds__(256) void fill_kernel(
    const int* __restrict__ ei1, const float* __restrict__ w1,
    const float* __restrict__ dis1, int* __restrict__ cur1,
    int* __restrict__ csrc1, float* __restrict__ coef1,
    const int* __restrict__ ei2, const float* __restrict__ w2,
    const float* __restrict__ dis2, int* __restrict__ cur2,
    int* __restrict__ csrc2, float* __restrict__ coef2) {
  int e = blockIdx.x * 256 + threadIdx.x;
  if (e >= N_EDGES) return;
  {
    int s = ei1[e], d = ei1[N_EDGES + e];
    int slot = atomicAdd(&cur1[d], 1);
    csrc1[slot] = s;
    coef1[slot] = w1[e] * dis1[s];
  }
  {
    int s = ei2[e], d = ei2[N_EDGES + e];
    int slot = atomicAdd(&cur2[d], 1);
    csrc2[slot] = s;
    coef2[slot] = w2[e] * dis2[s];
  }
}

// 5) GEMM: Y[r] = Xsel[r] @ W  for r in [0, 2N).  Row < N reads X0, else X1.
__global__ __launch_bounds__(256, 2) void gemm_kernel(
    const float* __restrict__ X0, const float* __restrict__ X1,
    const float* __restrict__ W, float* __restrict__ Y) {
  __shared__ float xsT[128 * 128];
  const int tid = threadIdx.x;
  const int rbase = blockIdx.x * 128;
  // stage transposed with XOR swizzle: addr(k,row) = k*128 + (row ^ (k & 28))
#pragma unroll
  for (int it = 0; it < 16; ++it) {
    int idx = it * 256 + tid;
    int row = idx >> 5;   // 0..127
    int k4 = idx & 31;    // float4 index along k
    int gr = rbase + row;
    float4 v = make_float4(0.f, 0.f, 0.f, 0.f);
    if (gr < 2 * N_NODES) {
      const float* src = (gr < N_NODES) ? (X0 + (size_t)gr * 128)
                                        : (X1 + (size_t)(gr - N_NODES) * 128);
      v = ((const float4*)src)[k4];
    }
    int k0 = k4 * 4;
    xsT[(k0 + 0) * 128 + (row ^ ((k0 + 0) & 28))] = v.x;
    xsT[(k0 + 1) * 128 + (row ^ ((k0 + 1) & 28))] = v.y;
    xsT[(k0 + 2) * 128 + (row ^ ((k0 + 2) & 28))] = v.z;
    xsT[(k0 + 3) * 128 + (row ^ ((k0 + 3) & 28))] = v.w;
  }
  __syncthreads();
  const int wv = __builtin_amdgcn_readfirstlane(tid >> 6);  // wave id 0..3
  const int c0 = wv * 32;                                   // wave-uniform col base
  const int lane = tid & 63;
  const int r2 = lane * 2;
  float acc0[32], acc1[32];
#pragma unroll
  for (int u = 0; u < 32; ++u) { acc0[u] = 0.f; acc1[u] = 0.f; }
  for (int k = 0; k < 128; ++k) {
    const float2 x = *(const float2*)&xsT[k * 128 + (r2 ^ (k & 28))];
    const float* __restrict__ wr = W + k * 128 + c0;  // uniform -> s_load
#pragma unroll
    for (int u = 0; u < 32; ++u) {
      float wval = wr[u];
      acc0[u] += x.x * wval;
      acc1[u] += x.y * wval;
    }
  }
  int gr0 = rbase + r2;
  if (gr0 < 2 * N_NODES) {
    float4* dst = (float4*)(Y + (size_t)gr0 * 128 + c0);
#pragma unroll
    for (int u = 0; u < 8; ++u)
      dst[u] = make_float4(acc0[4 * u], acc0[4 * u + 1], acc0[4 * u + 2], acc0[4 * u + 3]);
  }
  if (gr0 + 1 < 2 * N_NODES) {
    float4* dst = (float4*)(Y + (size_t)(gr0 + 1) * 128 + c0);
#pragma unroll
    for (int u = 0; u < 8; ++u)
      dst[u] = make_float4(acc1[4 * u], acc1[4 * u + 1], acc1[4 * u + 2], acc1[4 * u + 3]);
  }
}

// 6) layer-1 aggregate: out[i] = b + dis[i]^2 * H[i] + dis[i] * sum coef_e * H[src_e]
//    idx in [0,2N): graph1 nodes then graph2 nodes.  128 threads per node.
__global__ __launch_bounds__(256) void aggregate1_kernel(
    const int* __restrict__ rp1, const int* __restrict__ cs1,
    const float* __restrict__ cf1, const float* __restrict__ dis1,
    const int* __restrict__ rp2, const int* __restrict__ cs2,
    const float* __restrict__ cf2, const float* __restrict__ dis2,
    const float* __restrict__ H, const float* __restrict__ bias,
    float* __restrict__ out) {
  int idx = blockIdx.x * 2 + (threadIdx.x >> 7);
  int j = threadIdx.x & 127;
  const int *rp, *cs;
  const float *cf, *dis, *Hb;
  int node;
  if (idx < N_NODES) {
    rp = rp1; cs = cs1; cf = cf1; dis = dis1; node = idx; Hb = H;
  } else {
    rp = rp2; cs = cs2; cf = cf2; dis = dis2; node = idx - N_NODES;
    Hb = H + (size_t)N_NODES * 128;
  }
  float acc = edge_gather(cs, cf, rp[node], rp[node + 1], Hb, j);
  float di = dis[node];
  out[(size_t)idx * 128 + j] =
      bias[j] + di * di * Hb[(size_t)node * 128 + j] + di * acc;
}

// 7) layer-2 aggregate + diff-product + pool atomic.  2 node-pairs per block.
__global__ __launch_bounds__(256) void aggregate2_pool_kernel(
    const int* __restrict__ rp1, const int* __restrict__ cs1,
    const float* __restrict__ cf1, const float* __restrict__ dis1,
    const int* __restrict__ rp2, const int* __restrict__ cs2,
    const float* __restrict__ cf2, const float* __restrict__ dis2,
    const float* __restrict__ T,   // t1 at 0, t2 at N*128
    const float* __restrict__ X1,  // x11 at 0, x12 at N*128
    const float* __restrict__ b2, const int* __restrict__ batch,
    float* __restrict__ pool) {
  int i = blockIdx.x * 2 + (threadIdx.x >> 7);  // node index
  if (i >= N_NODES) return;
  int j = threadIdx.x & 127;
  const size_t off2 = (size_t)N_NODES * 128;
  const float bj = b2[j];
  float a1 = edge_gather(cs1, cf1, rp1[i], rp1[i + 1], T, j);
  float d1 = dis1[i];
  float x21 = bj + d1 * d1 * T[(size_t)i * 128 + j] + d1 * a1;
  float a2 = edge_gather(cs2, cf2, rp2[i], rp2[i + 1], T + off2, j);
  float d2 = dis2[i];
  float x22 = bj + d2 * d2 * T[off2 + (size_t)i * 128 + j] + d2 * a2;
  float v = (X1[off2 + (size_t)i * 128 + j] - X1[(size_t)i * 128 + j]) * (x22 - x21);
  atomicAdd(&pool[batch[i] * 128 + j], v);
}

// 8) per-graph mean + 4-layer MLP.  One block per graph, 128 threads.
__global__ __launch_bounds__(128) void mlp_kernel(
    const float* __restrict__ pool, const int* __restrict__ batch,
    const float* __restrict__ M1w, const float* __restrict__ M1b,
    const float* __restrict__ M2w, const float* __restrict__ M2b,
    const float* __restrict__ M3w, const float* __restrict__ M3b,
    const float* __restrict__ M4w, const float* __restrict__ M4b,
    float* __restrict__ out) {
  __shared__ float gv[128], t1[128], t2[64], t3[32];
  const int g = blockIdx.x, j = threadIdx.x;
  int lo, hi;
  { int a = 0, b = N_NODES; while (a < b) { int m = (a + b) >> 1; if (batch[m] < g) a = m + 1; else b = m; } lo = a; }
  { int a = lo, b = N_NODES; while (a < b) { int m = (a + b) >> 1; if (batch[m] < g + 1) a = m + 1; else b = m; } hi = a; }
  float cnt = (float)(hi - lo);
  if (cnt < 1.f) cnt = 1.f;
  gv[j] = pool[g * 128 + j] / cnt;
  __syncthreads();
  float a = M1b[j];
  for (int k = 0; k < 128; ++k) a += gv[k] * M1w[k * 128 + j];
  t1[j] = a;
  __syncthreads();
  if (j < 64) {
    float b = M2b[j];
    for (int k = 0; k < 128; ++k) b += t1[k] * M2w[k * 64 + j];
    t2[j] = b;
  }
  __syncthreads();
  if (j < 32) {
    float c = M3b[j];
    for (int k = 0; k < 64; ++k) c += t2[k] * M3w[k * 32 + j];
    t3[j] = c;
  }
  __syncthreads();
  if (j == 0) {
    float o = M4b[0];
    for (int k = 0; k < 32; ++k) o += t3[k] * M4w[k];
    out[g] = o;
  }
}

// ---------------------------------------------------------------------------
extern "C" void kernel_launch(void* const* d_in, const int* in_sizes, int n_in,
                              void* d_out, int out_size, void* d_ws, size_t ws_size,
                              hipStream_t stream) {
  const int* ei1 = (const int*)d_in[0];
  const float* w1 = (const float*)d_in[1];
  const int* ei2 = (const int*)d_in[2];
  const float* w2 = (const float*)d_in[3];
  const float* fm0 = (const float*)d_in[4];
  const float* fm1 = (const float*)d_in[5];
  const int* batch = (const int*)d_in[6];
  const float* W1 = (const float*)d_in[7];
  const float* b1 = (const float*)d_in[8];
  const float* W2 = (const float*)d_in[9];
  const float* b2 = (const float*)d_in[10];
  const float* M1w = (const float*)d_in[11];
  const float* M1b = (const float*)d_in[12];
  const float* M2w = (const float*)d_in[13];
  const float* M2b = (const float*)d_in[14];
  const float* M3w = (const float*)d_in[15];
  const float* M3b = (const float*)d_in[16];
  const float* M4w = (const float*)d_in[17];
  const float* M4b = (const float*)d_in[18];

  // workspace layout (element offsets, 16-element aligned)
  size_t off = 0;
  auto alloc = [&](size_t n) { size_t r = off; off += (n + 15) & ~(size_t)15; return r; };
  size_t o_deg1 = alloc(N_NODES);
  size_t o_deg2 = alloc(N_NODES);
  size_t o_hist1 = alloc(N_NODES);
  size_t o_hist2 = alloc(N_NODES);
  size_t o_pool = alloc(NGRAPH * 128);
  size_t zero_elems = off;  // everything above gets zeroed
  size_t o_rp1 = alloc(N_NODES + 1);
  size_t o_rp2 = alloc(N_NODES + 1);
  size_t o_cur1 = alloc(N_NODES);
  size_t o_cur2 = alloc(N_NODES);
  size_t o_cs1 = alloc(N_EDGES);
  size_t o_cs2 = alloc(N_EDGES);
  size_t o_cf1 = alloc(N_EDGES);
  size_t o_cf2 = alloc(N_EDGES);
  size_t o_h = alloc((size_t)2 * N_NODES * 128);
  size_t o_x1 = alloc((size_t)2 * N_NODES * 128);
  if (ws_size < off * sizeof(float)) return;  // insufficient workspace: fail loudly

  float* fbase = (float*)d_ws;
  int* ibase = (int*)d_ws;
  float* deg1 = fbase + o_deg1;
  float* deg2 = fbase + o_deg2;
  int* hist1 = ibase + o_hist1;
  int* hist2 = ibase + o_hist2;
  float* pool = fbase + o_pool;
  int* rp1 = ibase + o_rp1;
  int* rp2 = ibase + o_rp2;
  int* cur1 = ibase + o_cur1;
  int* cur2 = ibase + o_cur2;
  int* cs1 = ibase + o_cs1;
  int* cs2 = ibase + o_cs2;
  float* cf1 = fbase + o_cf1;
  float* cf2 = fbase + o_cf2;
  float* h = fbase + o_h;
  float* x1 = fbase + o_x1;

  hipMemsetAsync(d_ws, 0, zero_elems * sizeof(float), stream);

  edge_hist_kernel<<<(N_EDGES + 255) / 256, 256, 0, stream>>>(
      ei1, w1, ei2, w2, deg1, deg2, hist1, hist2);
  dis_kernel<<<(N_NODES + 255) / 256, 256, 0, stream>>>(deg1, deg2);
  scan_kernel<<<2, 1024, 0, stream>>>(hist1, hist2, rp1, rp2, cur1, cur2);
  fill_kernel<<<(N_EDGES + 255) / 256, 256, 0, stream>>>(
      ei1, w1, deg1, cur1, cs1, cf1, ei2, w2, deg2, cur2, cs2, cf2);
  // layer 1: h = [fm0; fm1] @ W1
  gemm_kernel<<<(2 * N_NODES + 127) / 128, 256, 0, stream>>>(fm0, fm1, W1, h);
  aggregate1_kernel<<<N_NODES, 256, 0, stream>>>(
      rp1, cs1, cf1, deg1, rp2, cs2, cf2, deg2, h, b1, x1);
  // layer 2: t = [x11; x12] @ W2 (overwrites h)
  gemm_kernel<<<(2 * N_NODES + 127) / 128, 256, 0, stream>>>(
      x1, x1 + (size_t)N_NODES * 128, W2, h);
  aggregate2_pool_kernel<<<(N_NODES + 1) / 2, 256, 0, stream>>>(
      rp1, cs1, cf1, deg1, rp2, cs2, cf2, deg2, h, x1, b2, batch, pool);
  mlp_kernel<<<NGRAPH, 128, 0, stream>>>(
      pool, batch, M1w, M1b, M2w, M2b, M3w, M3b, M4w, M4b, (float*)d_out);
}

// Round 3
// 729.199 us; speedup vs baseline: 1.3421x; 1.0986x over previous
//
#include <hip/hip_runtime.h>
#include <hip/hip_fp16.h>

#define N_NODES 50000
#define N_EDGES 800000
#define NGRAPH 64
#define NB 49  // scan blocks per graph: ceil(50000/1024)

// ---------------------------------------------------------------------------
// gather: 8 predicated independent row-gathers in flight; lane covers 2 feats
__device__ __forceinline__ float2 edge_gather8(
    const int2* __restrict__ ec, int beg, int end,
    const __half2* __restrict__ Hb2, int lane) {
  float2 a[8];
#pragma unroll
  for (int k = 0; k < 8; ++k) a[k] = make_float2(0.f, 0.f);
  for (int e = beg; e < end; e += 8) {
#pragma unroll
    for (int k = 0; k < 8; ++k) {
      if (e + k < end) {
        int2 p = ec[e + k];
        float c = __int_as_float(p.y);
        float2 hv = __half22float2(Hb2[(size_t)p.x * 64 + lane]);
        a[k].x += c * hv.x;
        a[k].y += c * hv.y;
      }
    }
  }
#pragma unroll
  for (int k = 0; k < 4; ++k) {
    a[k].x += a[k + 4].x;
    a[k].y += a[k + 4].y;
  }
  return make_float2((a[0].x + a[1].x) + (a[2].x + a[3].x),
                     (a[0].y + a[1].y) + (a[2].y + a[3].y));
}

// ---------------------------------------------------------------------------
// 1) edge histogram: weighted degree (float) + edge count per dst (int)
__global__ __launch_bounds__(256) void edge_hist_kernel(
    const int* __restrict__ ei1, const float* __restrict__ w1,
    const int* __restrict__ ei2, const float* __restrict__ w2,
    float* __restrict__ deg1, float* __restrict__ deg2,
    int* __restrict__ hist1, int* __restrict__ hist2) {
  int e = blockIdx.x * 256 + threadIdx.x;
  if (e >= N_EDGES) return;
  int d1 = ei1[N_EDGES + e];
  atomicAdd(&deg1[d1], w1[e]);
  atomicAdd(&hist1[d1], 1);
  int d2 = ei2[N_EDGES + e];
  atomicAdd(&deg2[d2], w2[e]);
  atomicAdd(&hist2[d2], 1);
}

// 2) dis = rsqrt(deg + 1)
__global__ __launch_bounds__(256) void dis_kernel(float* deg1, float* deg2) {
  int i = blockIdx.x * 256 + threadIdx.x;
  if (i >= N_NODES) return;
  deg1[i] = rsqrtf(deg1[i] + 1.0f);
  deg2[i] = rsqrtf(deg2[i] + 1.0f);
}

// 3a) per-1024-chunk sums.  grid = 2*NB, block 256.
__global__ __launch_bounds__(256) void blocksum_kernel(
    const int* __restrict__ h1, const int* __restrict__ h2,
    int* __restrict__ bsums) {
  int g = blockIdx.x >= NB;
  int b = blockIdx.x - g * NB;
  const int4* hist4 = (const int4*)(g ? h2 : h1);
  int tid = threadIdx.x, lane = tid & 63, wid = tid >> 6;
  int i4 = b * 256 + tid;
  int s = 0;
  if (i4 < N_NODES / 4) {
    int4 q = hist4[i4];
    s = (q.x + q.y) + (q.z + q.w);
  }
#pragma unroll
  for (int off = 32; off; off >>= 1) s += __shfl_down(s, off, 64);
  __shared__ int ws[4];
  if (lane == 0) ws[wid] = s;
  __syncthreads();
  if (tid == 0) bsums[blockIdx.x] = (ws[0] + ws[1]) + (ws[2] + ws[3]);
}

// 3b) scan the 2*NB chunk sums (wave w handles graph w).  1 block, 128 thr.
__global__ __launch_bounds__(128) void scanbsums_kernel(
    int* __restrict__ bsums, int* __restrict__ rp1, int* __restrict__ rp2) {
  int w = threadIdx.x >> 6, lane = threadIdx.x & 63;
  int v = (lane < NB) ? bsums[w * NB + lane] : 0;
  int incl = v;
#pragma unroll
  for (int off = 1; off < 64; off <<= 1) {
    int t = __shfl_up(incl, off, 64);
    if (lane >= off) incl += t;
  }
  if (lane < NB) bsums[w * NB + lane] = incl - v;
  if (lane == NB - 1) (w ? rp2 : rp1)[N_NODES] = incl;
}

// 3c) local scan + chunk offset -> rowptr & cursor.  grid = 2*NB, block 256.
__global__ __launch_bounds__(256) void localscan_kernel(
    const int* __restrict__ h1, const int* __restrict__ h2,
    const int* __restrict__ bsums,
    int* __restrict__ rp1, int* __restrict__ rp2,
    int* __restrict__ cur1, int* __restrict__ cur2) {
  int g = blockIdx.x >= NB;
  int b = blockIdx.x - g * NB;
  const int4* hist4 = (const int4*)(g ? h2 : h1);
  int* rp = g ? rp2 : rp1;
  int* cur = g ? cur2 : cur1;
  int tid = threadIdx.x, lane = tid & 63, wid = tid >> 6;
  int i4 = b * 256 + tid;
  int4 q = make_int4(0, 0, 0, 0);
  if (i4 < N_NODES / 4) q = hist4[i4];
  int e1 = q.x, e2 = q.x + q.y, e3 = e2 + q.z, s = e3 + q.w;
  int incl = s;
#pragma unroll
  for (int off = 1; off < 64; off <<= 1) {
    int t = __shfl_up(incl, off, 64);
    if (lane >= off) incl += t;
  }
  int texcl = incl - s;
  __shared__ int ws[4], wo[4];
  if (lane == 63) ws[wid] = incl;
  __syncthreads();
  if (tid == 0) {
    int r = 0;
#pragma unroll
    for (int w = 0; w < 4; ++w) { wo[w] = r; r += ws[w]; }
  }
  __syncthreads();
  int off0 = bsums[blockIdx.x] + wo[wid] + texcl;
  if (i4 < N_NODES / 4) {
    int4 r4 = make_int4(off0, off0 + e1, off0 + e2, off0 + e3);
    ((int4*)rp)[i4] = r4;
    ((int4*)cur)[i4] = r4;
  }
}

// 4) CSR fill; packed (src, coef) per slot
__global__ __launch_bounds__(256) void fill_kernel(
    const int* __restrict__ ei1, const float* __restrict__ w1,
    const float* __restrict__ dis1, int* __restrict__ cur1,
    int2* __restrict__ ec1,
    const int* __restrict__ ei2, const float* __restrict__ w2,
    const float* __restrict__ dis2, int* __restrict__ cur2,
    int2* __restrict__ ec2) {
  int e = blockIdx.x * 256 + threadIdx.x;
  if (e >= N_EDGES) return;
  {
    int s = ei1[e], d = ei1[N_EDGES + e];
    int slot = atomicAdd(&cur1[d], 1);
    ec1[slot] = make_int2(s, __float_as_int(w1[e] * dis1[s]));
  }
  {
    int s = ei2[e], d = ei2[N_EDGES + e];
    int slot = atomicAdd(&cur2[d], 1);
    ec2[slot] = make_int2(s, __float_as_int(w2[e] * dis2[s]));
  }
}

// 5) GEMM: Y[r] = Xsel[r] @ W, fp32 in, fp16 out.
__global__ __launch_bounds__(256, 2) void gemm_kernel(
    const float* __restrict__ X0, const float* __restrict__ X1,
    const float* __restrict__ W, __half* __restrict__ Y) {
  __shared__ float xsT[128 * 128];
  const int tid = threadIdx.x;
  const int rbase = blockIdx.x * 128;
#pragma unroll
  for (int it = 0; it < 16; ++it) {
    int idx = it * 256 + tid;
    int row = idx >> 5;
    int k4 = idx & 31;
    int gr = rbase + row;
    float4 v = make_float4(0.f, 0.f, 0.f, 0.f);
    if (gr < 2 * N_NODES) {
      const float* src = (gr < N_NODES) ? (X0 + (size_t)gr * 128)
                                        : (X1 + (size_t)(gr - N_NODES) * 128);
      v = ((const float4*)src)[k4];
    }
    int k0 = k4 * 4;
    xsT[(k0 + 0) * 128 + (row ^ ((k0 + 0) & 28))] = v.x;
    xsT[(k0 + 1) * 128 + (row ^ ((k0 + 1) & 28))] = v.y;
    xsT[(k0 + 2) * 128 + (row ^ ((k0 + 2) & 28))] = v.z;
    xsT[(k0 + 3) * 128 + (row ^ ((k0 + 3) & 28))] = v.w;
  }
  __syncthreads();
  const int wv = __builtin_amdgcn_readfirstlane(tid >> 6);
  const int c0 = wv * 32;
  const int lane = tid & 63;
  const int r2 = lane * 2;
  float acc0[32], acc1[32];
#pragma unroll
  for (int u = 0; u < 32; ++u) { acc0[u] = 0.f; acc1[u] = 0.f; }
  for (int k = 0; k < 128; ++k) {
    const float2 x = *(const float2*)&xsT[k * 128 + (r2 ^ (k & 28))];
    const float* __restrict__ wr = W + k * 128 + c0;
#pragma unroll
    for (int u = 0; u < 32; ++u) {
      float wval = wr[u];
      acc0[u] += x.x * wval;
      acc1[u] += x.y * wval;
    }
  }
  int gr0 = rbase + r2;
  if (gr0 < 2 * N_NODES) {
    __half2 hrow[16];
#pragma unroll
    for (int u = 0; u < 16; ++u)
      hrow[u] = __floats2half2_rn(acc0[2 * u], acc0[2 * u + 1]);
    float4* dst = (float4*)(Y + (size_t)gr0 * 128 + c0);
#pragma unroll
    for (int u = 0; u < 4; ++u) dst[u] = ((float4*)hrow)[u];
  }
  if (gr0 + 1 < 2 * N_NODES) {
    __half2 hrow[16];
#pragma unroll
    for (int u = 0; u < 16; ++u)
      hrow[u] = __floats2half2_rn(acc1[2 * u], acc1[2 * u + 1]);
    float4* dst = (float4*)(Y + (size_t)(gr0 + 1) * 128 + c0);
#pragma unroll
    for (int u = 0; u < 4; ++u) dst[u] = ((float4*)hrow)[u];
  }
}

// 6) layer-1 aggregate: one wave per node-index in [0,2N)
__global__ __launch_bounds__(256) void aggregate1_kernel(
    const int* __restrict__ rp1, const int2* __restrict__ ec1,
    const float* __restrict__ dis1,
    const int* __restrict__ rp2, const int2* __restrict__ ec2,
    const float* __restrict__ dis2,
    const __half* __restrict__ H, const float* __restrict__ bias,
    float* __restrict__ out) {
  int idx = blockIdx.x * 4 + (threadIdx.x >> 6);
  int lane = threadIdx.x & 63;
  const int* rp;
  const int2* ec;
  const float* dis;
  const __half2* Hb2;
  int node;
  if (idx < N_NODES) {
    rp = rp1; ec = ec1; dis = dis1; node = idx;
    Hb2 = (const __half2*)H;
  } else {
    rp = rp2; ec = ec2; dis = dis2; node = idx - N_NODES;
    Hb2 = (const __half2*)(H + (size_t)N_NODES * 128);
  }
  float2 acc = edge_gather8(ec, rp[node], rp[node + 1], Hb2, lane);
  float d = dis[node];
  float2 self = __half22float2(Hb2[(size_t)node * 64 + lane]);
  float2 bz = *(const float2*)&bias[lane * 2];
  float2 o;
  o.x = bz.x + d * d * self.x + d * acc.x;
  o.y = bz.y + d * d * self.y + d * acc.y;
  *(float2*)&out[(size_t)idx * 128 + lane * 2] = o;
}

// 7) layer-2 aggregate + diff-product + pool.  One wave per 4 consecutive nodes.
__global__ __launch_bounds__(256) void aggregate2_pool_kernel(
    const int* __restrict__ rp1, const int2* __restrict__ ec1,
    const float* __restrict__ dis1,
    const int* __restrict__ rp2, const int2* __restrict__ ec2,
    const float* __restrict__ dis2,
    const __half* __restrict__ T,   // t1 at 0, t2 at N*128
    const float* __restrict__ X1,   // x11 at 0, x12 at N*128 (fp32)
    const float* __restrict__ b2, const int* __restrict__ batch,
    float* __restrict__ pool) {
  int lane = threadIdx.x & 63;
  int wnode = (blockIdx.x * 4 + (threadIdx.x >> 6)) * 4;
  const __half2* T1 = (const __half2*)T;
  const __half2* T2 = (const __half2*)(T + (size_t)N_NODES * 128);
  const size_t off2 = (size_t)N_NODES * 128;
  float2 bz = *(const float2*)&b2[lane * 2];
  float2 pacc = make_float2(0.f, 0.f);
  int curg = -1;
  for (int t = 0; t < 4; ++t) {
    int i = wnode + t;
    if (i >= N_NODES) break;
    float2 a1 = edge_gather8(ec1, rp1[i], rp1[i + 1], T1, lane);
    float d1 = dis1[i];
    float2 s1 = __half22float2(T1[(size_t)i * 64 + lane]);
    float2 a2 = edge_gather8(ec2, rp2[i], rp2[i + 1], T2, lane);
    float d2 = dis2[i];
    float2 s2 = __half22float2(T2[(size_t)i * 64 + lane]);
    float2 x21, x22;
    x21.x = bz.x + d1 * d1 * s1.x + d1 * a1.x;
    x21.y = bz.y + d1 * d1 * s1.y + d1 * a1.y;
    x22.x = bz.x + d2 * d2 * s2.x + d2 * a2.x;
    x22.y = bz.y + d2 * d2 * s2.y + d2 * a2.y;
    float2 xa = *(const float2*)&X1[(size_t)i * 128 + lane * 2];
    float2 xb = *(const float2*)&X1[off2 + (size_t)i * 128 + lane * 2];
    float2 v;
    v.x = (xb.x - xa.x) * (x22.x - x21.x);
    v.y = (xb.y - xa.y) * (x22.y - x21.y);
    int g = batch[i];
    if (g != curg) {
      if (curg >= 0) {
        atomicAdd(&pool[curg * 128 + lane * 2], pacc.x);
        atomicAdd(&pool[curg * 128 + lane * 2 + 1], pacc.y);
      }
      pacc = make_float2(0.f, 0.f);
      curg = g;
    }
    pacc.x += v.x;
    pacc.y += v.y;
  }
  if (curg >= 0) {
    atomicAdd(&pool[curg * 128 + lane * 2], pacc.x);
    atomicAdd(&pool[curg * 128 + lane * 2 + 1], pacc.y);
  }
}

// 8) per-graph mean + 4-layer MLP.  One block per graph, 128 threads.
__global__ __launch_bounds__(128) void mlp_kernel(
    const float* __restrict__ pool, const int* __restrict__ batch,
    const float* __restrict__ M1w, const float* __restrict__ M1b,
    const float* __restrict__ M2w, const float* __restrict__ M2b,
    const float* __restrict__ M3w, const float* __restrict__ M3b,
    const float* __restrict__ M4w, const float* __restrict__ M4b,
    float* __restrict__ out) {
  __shared__ float gv[128], t1[128], t2[64], t3[32];
  const int g = blockIdx.x, j = threadIdx.x;
  int lo, hi;
  { int a = 0, b = N_NODES; while (a < b) { int m = (a + b) >> 1; if (batch[m] < g) a = m + 1; else b = m; } lo = a; }
  { int a = lo, b = N_NODES; while (a < b) { int m = (a + b) >> 1; if (batch[m] < g + 1) a = m + 1; else b = m; } hi = a; }
  float cnt = (float)(hi - lo);
  if (cnt < 1.f) cnt = 1.f;
  gv[j] = pool[g * 128 + j] / cnt;
  __syncthreads();
  float a = M1b[j];
  for (int k = 0; k < 128; ++k) a += gv[k] * M1w[k * 128 + j];
  t1[j] = a;
  __syncthreads();
  if (j < 64) {
    float b = M2b[j];
    for (int k = 0; k < 128; ++k) b += t1[k] * M2w[k * 64 + j];
    t2[j] = b;
  }
  __syncthreads();
  if (j < 32) {
    float c = M3b[j];
    for (int k = 0; k < 64; ++k) c += t2[k] * M3w[k * 32 + j];
    t3[j] = c;
  }
  __syncthreads();
  if (j == 0) {
    float o = M4b[0];
    for (int k = 0; k < 32; ++k) o += t3[k] * M4w[k];
    out[g] = o;
  }
}

// ---------------------------------------------------------------------------
extern "C" void kernel_launch(void* const* d_in, const int* in_sizes, int n_in,
                              void* d_out, int out_size, void* d_ws, size_t ws_size,
                              hipStream_t stream) {
  const int* ei1 = (const int*)d_in[0];
  const float* w1 = (const float*)d_in[1];
  const int* ei2 = (const int*)d_in[2];
  const float* w2 = (const float*)d_in[3];
  const float* fm0 = (const float*)d_in[4];
  const float* fm1 = (const float*)d_in[5];
  const int* batch = (const int*)d_in[6];
  const float* W1 = (const float*)d_in[7];
  const float* b1 = (const float*)d_in[8];
  const float* W2 = (const float*)d_in[9];
  const float* b2 = (const float*)d_in[10];
  const float* M1w = (const float*)d_in[11];
  const float* M1b = (const float*)d_in[12];
  const float* M2w = (const float*)d_in[13];
  const float* M2b = (const float*)d_in[14];
  const float* M3w = (const float*)d_in[15];
  const float* M3b = (const float*)d_in[16];
  const float* M4w = (const float*)d_in[17];
  const float* M4b = (const float*)d_in[18];

  // workspace layout (float-element offsets, 16-element aligned)
  size_t off = 0;
  auto alloc = [&](size_t n) { size_t r = off; off += (n + 15) & ~(size_t)15; return r; };
  size_t o_deg1 = alloc(N_NODES);
  size_t o_deg2 = alloc(N_NODES);
  size_t o_hist1 = alloc(N_NODES);
  size_t o_hist2 = alloc(N_NODES);
  size_t o_pool = alloc(NGRAPH * 128);
  size_t zero_elems = off;  // everything above gets zeroed
  size_t o_rp1 = alloc(N_NODES + 1);
  size_t o_rp2 = alloc(N_NODES + 1);
  size_t o_cur1 = alloc(N_NODES);
  size_t o_cur2 = alloc(N_NODES);
  size_t o_bsums = alloc(2 * NB);
  size_t o_ec1 = alloc((size_t)2 * N_EDGES);   // int2 per edge
  size_t o_ec2 = alloc((size_t)2 * N_EDGES);
  size_t o_h = alloc((size_t)N_NODES * 128);   // 2N*128 halves = N*128 floats
  size_t o_x1 = alloc((size_t)2 * N_NODES * 128);
  if (ws_size < off * sizeof(float)) return;  // insufficient workspace: fail loudly

  float* fbase = (float*)d_ws;
  int* ibase = (int*)d_ws;
  float* deg1 = fbase + o_deg1;
  float* deg2 = fbase + o_deg2;
  int* hist1 = ibase + o_hist1;
  int* hist2 = ibase + o_hist2;
  float* pool = fbase + o_pool;
  int* rp1 = ibase + o_rp1;
  int* rp2 = ibase + o_rp2;
  int* cur1 = ibase + o_cur1;
  int* cur2 = ibase + o_cur2;
  int* bsums = ibase + o_bsums;
  int2* ec1 = (int2*)(fbase + o_ec1);
  int2* ec2 = (int2*)(fbase + o_ec2);
  __half* h = (__half*)(fbase + o_h);
  float* x1 = fbase + o_x1;

  hipMemsetAsync(d_ws, 0, zero_elems * sizeof(float), stream);

  edge_hist_kernel<<<(N_EDGES + 255) / 256, 256, 0, stream>>>(
      ei1, w1, ei2, w2, deg1, deg2, hist1, hist2);
  dis_kernel<<<(N_NODES + 255) / 256, 256, 0, stream>>>(deg1, deg2);
  blocksum_kernel<<<2 * NB, 256, 0, stream>>>(hist1, hist2, bsums);
  scanbsums_kernel<<<1, 128, 0, stream>>>(bsums, rp1, rp2);
  localscan_kernel<<<2 * NB, 256, 0, stream>>>(
      hist1, hist2, bsums, rp1, rp2, cur1, cur2);
  fill_kernel<<<(N_EDGES + 255) / 256, 256, 0, stream>>>(
      ei1, w1, deg1, cur1, ec1, ei2, w2, deg2, cur2, ec2);
  // layer 1: h = [fm0; fm1] @ W1  (fp16 out)
  gemm_kernel<<<(2 * N_NODES + 127) / 128, 256, 0, stream>>>(fm0, fm1, W1, h);
  aggregate1_kernel<<<(2 * N_NODES + 3) / 4, 256, 0, stream>>>(
      rp1, ec1, deg1, rp2, ec2, deg2, h, b1, x1);
  // layer 2: t = [x11; x12] @ W2 (overwrites h, fp16)
  gemm_kernel<<<(2 * N_NODES + 127) / 128, 256, 0, stream>>>(
      x1, x1 + (size_t)N_NODES * 128, W2, h);
  aggregate2_pool_kernel<<<N_NODES / 16, 256, 0, stream>>>(
      rp1, ec1, deg1, rp2, ec2, deg2, h, x1, b2, batch, pool);
  mlp_kernel<<<NGRAPH, 128, 0, stream>>>(
      pool, batch, M1w, M1b, M2w, M2b, M3w, M3b, M4w, M4b, (float*)d_out);
}

// Round 4
// 655.077 us; speedup vs baseline: 1.4940x; 1.1132x over previous
//
#include <hip/hip_runtime.h>
#include <hip/hip_fp16.h>

#define N_NODES 50000
#define N_EDGES 800000
#define NGRAPH 64
#define NB 49  // scan blocks per graph: ceil(50000/1024)

// packed edge: u32 = src (u16, N<65536) | fp16 weight << 16
__device__ __forceinline__ float pk_w(unsigned p) {
  return __half2float(__ushort_as_half((unsigned short)(p >> 16)));
}
__device__ __forceinline__ unsigned pk_src(unsigned p) { return p & 0xFFFFu; }

// ---------------------------------------------------------------------------
// gather: 8 predicated independent row-gathers in flight; lane covers 2 feats
// returns sum of w_e * H'[src_e][2*lane..2*lane+1]
__device__ __forceinline__ float2 edge_gather8(
    const unsigned* __restrict__ ec, int beg, int end,
    const __half2* __restrict__ Hb2, int lane) {
  float2 a[8];
#pragma unroll
  for (int k = 0; k < 8; ++k) a[k] = make_float2(0.f, 0.f);
  for (int e = beg; e < end; e += 8) {
#pragma unroll
    for (int k = 0; k < 8; ++k) {
      if (e + k < end) {
        unsigned p = ec[e + k];
        float c = pk_w(p);
        float2 hv = __half22float2(Hb2[(size_t)pk_src(p) * 64 + lane]);
        a[k].x += c * hv.x;
        a[k].y += c * hv.y;
      }
    }
  }
#pragma unroll
  for (int k = 0; k < 4; ++k) {
    a[k].x += a[k + 4].x;
    a[k].y += a[k + 4].y;
  }
  return make_float2((a[0].x + a[1].x) + (a[2].x + a[3].x),
                     (a[0].y + a[1].y) + (a[2].y + a[3].y));
}

// ---------------------------------------------------------------------------
// 1) edge histogram: edge count per dst only (int atomics)
__global__ __launch_bounds__(256) void edge_hist_kernel(
    const int* __restrict__ ei1, const int* __restrict__ ei2,
    int* __restrict__ hist1, int* __restrict__ hist2) {
  int e = blockIdx.x * 256 + threadIdx.x;
  if (e >= N_EDGES) return;
  atomicAdd(&hist1[ei1[N_EDGES + e]], 1);
  atomicAdd(&hist2[ei2[N_EDGES + e]], 1);
}

// 3a) per-1024-chunk sums.  grid = 2*NB, block 256.
__global__ __launch_bounds__(256) void blocksum_kernel(
    const int* __restrict__ h1, const int* __restrict__ h2,
    int* __restrict__ bsums) {
  int g = blockIdx.x >= NB;
  int b = blockIdx.x - g * NB;
  const int4* hist4 = (const int4*)(g ? h2 : h1);
  int tid = threadIdx.x, lane = tid & 63, wid = tid >> 6;
  int i4 = b * 256 + tid;
  int s = 0;
  if (i4 < N_NODES / 4) {
    int4 q = hist4[i4];
    s = (q.x + q.y) + (q.z + q.w);
  }
#pragma unroll
  for (int off = 32; off; off >>= 1) s += __shfl_down(s, off, 64);
  __shared__ int ws[4];
  if (lane == 0) ws[wid] = s;
  __syncthreads();
  if (tid == 0) bsums[blockIdx.x] = (ws[0] + ws[1]) + (ws[2] + ws[3]);
}

// 3b) scan the 2*NB chunk sums (wave w handles graph w).  1 block, 128 thr.
__global__ __launch_bounds__(128) void scanbsums_kernel(
    int* __restrict__ bsums, int* __restrict__ rp1, int* __restrict__ rp2) {
  int w = threadIdx.x >> 6, lane = threadIdx.x & 63;
  int v = (lane < NB) ? bsums[w * NB + lane] : 0;
  int incl = v;
#pragma unroll
  for (int off = 1; off < 64; off <<= 1) {
    int t = __shfl_up(incl, off, 64);
    if (lane >= off) incl += t;
  }
  if (lane < NB) bsums[w * NB + lane] = incl - v;
  if (lane == NB - 1) (w ? rp2 : rp1)[N_NODES] = incl;
}

// 3c) local scan + chunk offset -> rowptr & cursor.  grid = 2*NB, block 256.
__global__ __launch_bounds__(256) void localscan_kernel(
    const int* __restrict__ h1, const int* __restrict__ h2,
    const int* __restrict__ bsums,
    int* __restrict__ rp1, int* __restrict__ rp2,
    int* __restrict__ cur1, int* __restrict__ cur2) {
  int g = blockIdx.x >= NB;
  int b = blockIdx.x - g * NB;
  const int4* hist4 = (const int4*)(g ? h2 : h1);
  int* rp = g ? rp2 : rp1;
  int* cur = g ? cur2 : cur1;
  int tid = threadIdx.x, lane = tid & 63, wid = tid >> 6;
  int i4 = b * 256 + tid;
  int4 q = make_int4(0, 0, 0, 0);
  if (i4 < N_NODES / 4) q = hist4[i4];
  int e1 = q.x, e2 = q.x + q.y, e3 = e2 + q.z, s = e3 + q.w;
  int incl = s;
#pragma unroll
  for (int off = 1; off < 64; off <<= 1) {
    int t = __shfl_up(incl, off, 64);
    if (lane >= off) incl += t;
  }
  int texcl = incl - s;
  __shared__ int ws[4], wo[4];
  if (lane == 63) ws[wid] = incl;
  __syncthreads();
  if (tid == 0) {
    int r = 0;
#pragma unroll
    for (int w = 0; w < 4; ++w) { wo[w] = r; r += ws[w]; }
  }
  __syncthreads();
  int off0 = bsums[blockIdx.x] + wo[wid] + texcl;
  if (i4 < N_NODES / 4) {
    int4 r4 = make_int4(off0, off0 + e1, off0 + e2, off0 + e3);
    ((int4*)rp)[i4] = r4;
    ((int4*)cur)[i4] = r4;
  }
}

// 4) CSR fill; packed (src u16 | w fp16) per slot.  No dis dependence.
__global__ __launch_bounds__(256) void fill_kernel(
    const int* __restrict__ ei1, const float* __restrict__ w1,
    int* __restrict__ cur1, unsigned* __restrict__ ec1,
    const int* __restrict__ ei2, const float* __restrict__ w2,
    int* __restrict__ cur2, unsigned* __restrict__ ec2) {
  int e = blockIdx.x * 256 + threadIdx.x;
  if (e >= N_EDGES) return;
  {
    int s = ei1[e], d = ei1[N_EDGES + e];
    int slot = atomicAdd(&cur1[d], 1);
    ec1[slot] = (unsigned)s |
                ((unsigned)__half_as_ushort(__float2half(w1[e])) << 16);
  }
  {
    int s = ei2[e], d = ei2[N_EDGES + e];
    int slot = atomicAdd(&cur2[d], 1);
    ec2[slot] = (unsigned)s |
                ((unsigned)__half_as_ushort(__float2half(w2[e])) << 16);
  }
}

// 4b) weighted degree from CSR (sequential reads) -> dis = rsqrt(1 + sum w)
__global__ __launch_bounds__(256) void degdis_kernel(
    const int* __restrict__ rp1, const unsigned* __restrict__ ec1,
    const int* __restrict__ rp2, const unsigned* __restrict__ ec2,
    float* __restrict__ dis1, float* __restrict__ dis2) {
  int i = blockIdx.x * 256 + threadIdx.x;
  if (i >= 2 * N_NODES) return;
  const int* rp;
  const unsigned* ec;
  float* dis;
  int node;
  if (i < N_NODES) { rp = rp1; ec = ec1; dis = dis1; node = i; }
  else { rp = rp2; ec = ec2; dis = dis2; node = i - N_NODES; }
  float s = 1.0f;  // self-loop weight
  int e0 = rp[node], e1 = rp[node + 1];
  for (int e = e0; e < e1; ++e) s += pk_w(ec[e]);
  dis[node] = rsqrtf(s);
}

// 5) GEMM: Y[r] = dis[r] * (Xsel[r] @ W), fp32 in, fp16 out (dis folded in).
__global__ __launch_bounds__(256, 2) void gemm_kernel(
    const float* __restrict__ X0, const float* __restrict__ X1,
    const float* __restrict__ W,
    const float* __restrict__ dis1, const float* __restrict__ dis2,
    __half* __restrict__ Y) {
  __shared__ float xsT[128 * 128];
  const int tid = threadIdx.x;
  const int rbase = blockIdx.x * 128;
#pragma unroll
  for (int it = 0; it < 16; ++it) {
    int idx = it * 256 + tid;
    int row = idx >> 5;
    int k4 = idx & 31;
    int gr = rbase + row;
    float4 v = make_float4(0.f, 0.f, 0.f, 0.f);
    if (gr < 2 * N_NODES) {
      const float* src = (gr < N_NODES) ? (X0 + (size_t)gr * 128)
                                        : (X1 + (size_t)(gr - N_NODES) * 128);
      v = ((const float4*)src)[k4];
    }
    int k0 = k4 * 4;
    xsT[(k0 + 0) * 128 + (row ^ ((k0 + 0) & 28))] = v.x;
    xsT[(k0 + 1) * 128 + (row ^ ((k0 + 1) & 28))] = v.y;
    xsT[(k0 + 2) * 128 + (row ^ ((k0 + 2) & 28))] = v.z;
    xsT[(k0 + 3) * 128 + (row ^ ((k0 + 3) & 28))] = v.w;
  }
  __syncthreads();
  const int wv = __builtin_amdgcn_readfirstlane(tid >> 6);
  const int c0 = wv * 32;
  const int lane = tid & 63;
  const int r2 = lane * 2;
  float acc0[32], acc1[32];
#pragma unroll
  for (int u = 0; u < 32; ++u) { acc0[u] = 0.f; acc1[u] = 0.f; }
  for (int k = 0; k < 128; ++k) {
    const float2 x = *(const float2*)&xsT[k * 128 + (r2 ^ (k & 28))];
    const float* __restrict__ wr = W + k * 128 + c0;
#pragma unroll
    for (int u = 0; u < 32; ++u) {
      float wval = wr[u];
      acc0[u] += x.x * wval;
      acc1[u] += x.y * wval;
    }
  }
  int gr0 = rbase + r2;
  if (gr0 < 2 * N_NODES) {
    float dsc = (gr0 < N_NODES) ? dis1[gr0] : dis2[gr0 - N_NODES];
    __half2 hrow[16];
#pragma unroll
    for (int u = 0; u < 16; ++u)
      hrow[u] = __floats2half2_rn(dsc * acc0[2 * u], dsc * acc0[2 * u + 1]);
    float4* dst = (float4*)(Y + (size_t)gr0 * 128 + c0);
#pragma unroll
    for (int u = 0; u < 4; ++u) dst[u] = ((float4*)hrow)[u];
  }
  if (gr0 + 1 < 2 * N_NODES) {
    int gr1 = gr0 + 1;
    float dsc = (gr1 < N_NODES) ? dis1[gr1] : dis2[gr1 - N_NODES];
    __half2 hrow[16];
#pragma unroll
    for (int u = 0; u < 16; ++u)
      hrow[u] = __floats2half2_rn(dsc * acc1[2 * u], dsc * acc1[2 * u + 1]);
    float4* dst = (float4*)(Y + (size_t)gr1 * 128 + c0);
#pragma unroll
    for (int u = 0; u < 4; ++u) dst[u] = ((float4*)hrow)[u];
  }
}

// 6) layer-1 aggregate: out[i] = b + dis_i * (H'[i] + sum w_e H'[src_e])
//    one wave per node-index in [0,2N)
__global__ __launch_bounds__(256) void aggregate1_kernel(
    const int* __restrict__ rp1, const unsigned* __restrict__ ec1,
    const float* __restrict__ dis1,
    const int* __restrict__ rp2, const unsigned* __restrict__ ec2,
    const float* __restrict__ dis2,
    const __half* __restrict__ H, const float* __restrict__ bias,
    float* __restrict__ out) {
  int idx = blockIdx.x * 4 + (threadIdx.x >> 6);
  int lane = threadIdx.x & 63;
  const int* rp;
  const unsigned* ec;
  const float* dis;
  const __half2* Hb2;
  int node;
  if (idx < N_NODES) {
    rp = rp1; ec = ec1; dis = dis1; node = idx;
    Hb2 = (const __half2*)H;
  } else {
    rp = rp2; ec = ec2; dis = dis2; node = idx - N_NODES;
    Hb2 = (const __half2*)(H + (size_t)N_NODES * 128);
  }
  float2 acc = edge_gather8(ec, rp[node], rp[node + 1], Hb2, lane);
  float d = dis[node];
  float2 self = __half22float2(Hb2[(size_t)node * 64 + lane]);
  float2 bz = *(const float2*)&bias[lane * 2];
  float2 o;
  o.x = bz.x + d * (self.x + acc.x);
  o.y = bz.y + d * (self.y + acc.y);
  *(float2*)&out[(size_t)idx * 128 + lane * 2] = o;
}

// 7) layer-2 aggregate + diff-product + pool.  One wave per 4 consecutive nodes.
__global__ __launch_bounds__(256) void aggregate2_pool_kernel(
    const int* __restrict__ rp1, const unsigned* __restrict__ ec1,
    const float* __restrict__ dis1,
    const int* __restrict__ rp2, const unsigned* __restrict__ ec2,
    const float* __restrict__ dis2,
    const __half* __restrict__ T,   // t1' at 0, t2' at N*128
    const float* __restrict__ X1,   // x11 at 0, x12 at N*128 (fp32)
    const float* __restrict__ b2, const int* __restrict__ batch,
    float* __restrict__ pool) {
  int lane = threadIdx.x & 63;
  int wnode = (blockIdx.x * 4 + (threadIdx.x >> 6)) * 4;
  const __half2* T1 = (const __half2*)T;
  const __half2* T2 = (const __half2*)(T + (size_t)N_NODES * 128);
  const size_t off2 = (size_t)N_NODES * 128;
  float2 bz = *(const float2*)&b2[lane * 2];
  float2 pacc = make_float2(0.f, 0.f);
  int curg = -1;
  for (int t = 0; t < 4; ++t) {
    int i = wnode + t;
    if (i >= N_NODES) break;
    float2 a1 = edge_gather8(ec1, rp1[i], rp1[i + 1], T1, lane);
    float d1 = dis1[i];
    float2 s1 = __half22float2(T1[(size_t)i * 64 + lane]);
    float2 a2 = edge_gather8(ec2, rp2[i], rp2[i + 1], T2, lane);
    float d2 = dis2[i];
    float2 s2 = __half22float2(T2[(size_t)i * 64 + lane]);
    float2 x21, x22;
    x21.x = bz.x + d1 * (s1.x + a1.x);
    x21.y = bz.y + d1 * (s1.y + a1.y);
    x22.x = bz.x + d2 * (s2.x + a2.x);
    x22.y = bz.y + d2 * (s2.y + a2.y);
    float2 xa = *(const float2*)&X1[(size_t)i * 128 + lane * 2];
    float2 xb = *(const float2*)&X1[off2 + (size_t)i * 128 + lane * 2];
    float2 v;
    v.x = (xb.x - xa.x) * (x22.x - x21.x);
    v.y = (xb.y - xa.y) * (x22.y - x21.y);
    int g = batch[i];
    if (g != curg) {
      if (curg >= 0) {
        atomicAdd(&pool[curg * 128 + lane * 2], pacc.x);
        atomicAdd(&pool[curg * 128 + lane * 2 + 1], pacc.y);
      }
      pacc = make_float2(0.f, 0.f);
      curg = g;
    }
    pacc.x += v.x;
    pacc.y += v.y;
  }
  if (curg >= 0) {
    atomicAdd(&pool[curg * 128 + lane * 2], pacc.x);
    atomicAdd(&pool[curg * 128 + lane * 2 + 1], pacc.y);
  }
}

// 8) per-graph mean + 4-layer MLP.  One block per graph, 128 threads.
__global__ __launch_bounds__(128) void mlp_kernel(
    const float* __restrict__ pool, const int* __restrict__ batch,
    const float* __restrict__ M1w, const float* __restrict__ M1b,
    const float* __restrict__ M2w, const float* __restrict__ M2b,
    const float* __restrict__ M3w, const float* __restrict__ M3b,
    const float* __restrict__ M4w, const float* __restrict__ M4b,
    float* __restrict__ out) {
  __shared__ float gv[128], t1[128], t2[64], t3[32];
  const int g = blockIdx.x, j = threadIdx.x;
  int lo, hi;
  { int a = 0, b = N_NODES; while (a < b) { int m = (a + b) >> 1; if (batch[m] < g) a = m + 1; else b = m; } lo = a; }
  { int a = lo, b = N_NODES; while (a < b) { int m = (a + b) >> 1; if (batch[m] < g + 1) a = m + 1; else b = m; } hi = a; }
  float cnt = (float)(hi - lo);
  if (cnt < 1.f) cnt = 1.f;
  gv[j] = pool[g * 128 + j] / cnt;
  __syncthreads();
  float a = M1b[j];
  for (int k = 0; k < 128; ++k) a += gv[k] * M1w[k * 128 + j];
  t1[j] = a;
  __syncthreads();
  if (j < 64) {
    float b = M2b[j];
    for (int k = 0; k < 128; ++k) b += t1[k] * M2w[k * 64 + j];
    t2[j] = b;
  }
  __syncthreads();
  if (j < 32) {
    float c = M3b[j];
    for (int k = 0; k < 64; ++k) c += t2[k] * M3w[k * 32 + j];
    t3[j] = c;
  }
  __syncthreads();
  if (j == 0) {
    float o = M4b[0];
    for (int k = 0; k < 32; ++k) o += t3[k] * M4w[k];
    out[g] = o;
  }
}

// ---------------------------------------------------------------------------
extern "C" void kernel_launch(void* const* d_in, const int* in_sizes, int n_in,
                              void* d_out, int out_size, void* d_ws, size_t ws_size,
                              hipStream_t stream) {
  const int* ei1 = (const int*)d_in[0];
  const float* w1 = (const float*)d_in[1];
  const int* ei2 = (const int*)d_in[2];
  const float* w2 = (const float*)d_in[3];
  const float* fm0 = (const float*)d_in[4];
  const float* fm1 = (const float*)d_in[5];
  const int* batch = (const int*)d_in[6];
  const float* W1 = (const float*)d_in[7];
  const float* b1 = (const float*)d_in[8];
  const float* W2 = (const float*)d_in[9];
  const float* b2 = (const float*)d_in[10];
  const float* M1w = (const float*)d_in[11];
  const float* M1b = (const float*)d_in[12];
  const float* M2w = (const float*)d_in[13];
  const float* M2b = (const float*)d_in[14];
  const float* M3w = (const float*)d_in[15];
  const float* M3b = (const float*)d_in[16];
  const float* M4w = (const float*)d_in[17];
  const float* M4b = (const float*)d_in[18];

  // workspace layout (float-element offsets, 16-element aligned)
  size_t off = 0;
  auto alloc = [&](size_t n) { size_t r = off; off += (n + 15) & ~(size_t)15; return r; };
  size_t o_hist1 = alloc(N_NODES);
  size_t o_hist2 = alloc(N_NODES);
  size_t o_pool = alloc(NGRAPH * 128);
  size_t zero_elems = off;  // everything above gets zeroed
  size_t o_dis1 = alloc(N_NODES);
  size_t o_dis2 = alloc(N_NODES);
  size_t o_rp1 = alloc(N_NODES + 1);
  size_t o_rp2 = alloc(N_NODES + 1);
  size_t o_cur1 = alloc(N_NODES);
  size_t o_cur2 = alloc(N_NODES);
  size_t o_bsums = alloc(2 * NB);
  size_t o_ec1 = alloc(N_EDGES);               // u32 per edge
  size_t o_ec2 = alloc(N_EDGES);
  size_t o_h = alloc((size_t)N_NODES * 128);   // 2N*128 halves = N*128 floats
  size_t o_x1 = alloc((size_t)2 * N_NODES * 128);
  if (ws_size < off * sizeof(float)) return;  // insufficient workspace: fail loudly

  float* fbase = (float*)d_ws;
  int* ibase = (int*)d_ws;
  int* hist1 = ibase + o_hist1;
  int* hist2 = ibase + o_hist2;
  float* pool = fbase + o_pool;
  float* dis1 = fbase + o_dis1;
  float* dis2 = fbase + o_dis2;
  int* rp1 = ibase + o_rp1;
  int* rp2 = ibase + o_rp2;
  int* cur1 = ibase + o_cur1;
  int* cur2 = ibase + o_cur2;
  int* bsums = ibase + o_bsums;
  unsigned* ec1 = (unsigned*)(fbase + o_ec1);
  unsigned* ec2 = (unsigned*)(fbase + o_ec2);
  __half* h = (__half*)(fbase + o_h);
  float* x1 = fbase + o_x1;

  hipMemsetAsync(d_ws, 0, zero_elems * sizeof(float), stream);

  edge_hist_kernel<<<(N_EDGES + 255) / 256, 256, 0, stream>>>(
      ei1, ei2, hist1, hist2);
  blocksum_kernel<<<2 * NB, 256, 0, stream>>>(hist1, hist2, bsums);
  scanbsums_kernel<<<1, 128, 0, stream>>>(bsums, rp1, rp2);
  localscan_kernel<<<2 * NB, 256, 0, stream>>>(
      hist1, hist2, bsums, rp1, rp2, cur1, cur2);
  fill_kernel<<<(N_EDGES + 255) / 256, 256, 0, stream>>>(
      ei1, w1, cur1, ec1, ei2, w2, cur2, ec2);
  degdis_kernel<<<(2 * N_NODES + 255) / 256, 256, 0, stream>>>(
      rp1, ec1, rp2, ec2, dis1, dis2);
  // layer 1: h' = dis * ([fm0; fm1] @ W1)  (fp16 out)
  gemm_kernel<<<(2 * N_NODES + 127) / 128, 256, 0, stream>>>(
      fm0, fm1, W1, dis1, dis2, h);
  aggregate1_kernel<<<(2 * N_NODES + 3) / 4, 256, 0, stream>>>(
      rp1, ec1, dis1, rp2, ec2, dis2, h, b1, x1);
  // layer 2: t' = dis * ([x11; x12] @ W2) (overwrites h, fp16)
  gemm_kernel<<<(2 * N_NODES + 127) / 128, 256, 0, stream>>>(
      x1, x1 + (size_t)N_NODES * 128, W2, dis1, dis2, h);
  aggregate2_pool_kernel<<<N_NODES / 16, 256, 0, stream>>>(
      rp1, ec1, dis1, rp2, ec2, dis2, h, x1, b2, batch, pool);
  mlp_kernel<<<NGRAPH, 128, 0, stream>>>(
      pool, batch, M1w, M1b, M2w, M2b, M3w, M3b, M4w, M4b, (float*)d_out);
}

// Round 5
// 478.615 us; speedup vs baseline: 2.0448x; 1.3687x over previous
//
#include <hip/hip_runtime.h>
#include <hip/hip_fp16.h>

#define N_NODES 50000
#define N_EDGES 800000
#define NGRAPH 64
#define NB 49  // scan blocks per graph: ceil(50000/1024)

typedef _Float16 half8 __attribute__((ext_vector_type(8)));
typedef float f32x4 __attribute__((ext_vector_type(4)));

// packed edge: u32 = src (u16, N<65536) | fp16 weight << 16
__device__ __forceinline__ float pk_w(unsigned p) {
  return __half2float(__ushort_as_half((unsigned short)(p >> 16)));
}
__device__ __forceinline__ unsigned pk_src(unsigned p) { return p & 0xFFFFu; }

// ---------------------------------------------------------------------------
// group-of-16 gather: 4 nodes per wave, each 16-lane group owns one node.
// lane covers 8 features (16 B). unroll 8 -> 8 KB in flight per wave.
__device__ __forceinline__ void edge_gather_g16(
    const unsigned* __restrict__ ec, int beg, int end,
    const float4* __restrict__ Hb4, int fl, float2 a[4]) {
  for (int e = beg; e < end; e += 8) {
#pragma unroll
    for (int k = 0; k < 8; ++k) {
      if (e + k < end) {
        unsigned p = ec[e + k];
        float c = pk_w(p);
        float4 raw = Hb4[(size_t)pk_src(p) * 16 + fl];
        const __half2* hp = (const __half2*)&raw;
#pragma unroll
        for (int q = 0; q < 4; ++q) {
          float2 hv = __half22float2(hp[q]);
          a[q].x += c * hv.x;
          a[q].y += c * hv.y;
        }
      }
    }
  }
}

// ---------------------------------------------------------------------------
// 1) edge histogram: edge count per dst (int atomics)
__global__ __launch_bounds__(256) void edge_hist_kernel(
    const int* __restrict__ ei1, const int* __restrict__ ei2,
    int* __restrict__ hist1, int* __restrict__ hist2) {
  int e = blockIdx.x * 256 + threadIdx.x;
  if (e >= N_EDGES) return;
  atomicAdd(&hist1[ei1[N_EDGES + e]], 1);
  atomicAdd(&hist2[ei2[N_EDGES + e]], 1);
}

// 3a) per-1024-chunk sums.  grid = 2*NB, block 256.
__global__ __launch_bounds__(256) void blocksum_kernel(
    const int* __restrict__ h1, const int* __restrict__ h2,
    int* __restrict__ bsums) {
  int g = blockIdx.x >= NB;
  int b = blockIdx.x - g * NB;
  const int4* hist4 = (const int4*)(g ? h2 : h1);
  int tid = threadIdx.x, lane = tid & 63, wid = tid >> 6;
  int i4 = b * 256 + tid;
  int s = 0;
  if (i4 < N_NODES / 4) {
    int4 q = hist4[i4];
    s = (q.x + q.y) + (q.z + q.w);
  }
#pragma unroll
  for (int off = 32; off; off >>= 1) s += __shfl_down(s, off, 64);
  __shared__ int ws[4];
  if (lane == 0) ws[wid] = s;
  __syncthreads();
  if (tid == 0) bsums[blockIdx.x] = (ws[0] + ws[1]) + (ws[2] + ws[3]);
}

// 3b) scan the 2*NB chunk sums (wave w handles graph w).  1 block, 128 thr.
__global__ __launch_bounds__(128) void scanbsums_kernel(
    int* __restrict__ bsums, int* __restrict__ rp1, int* __restrict__ rp2) {
  int w = threadIdx.x >> 6, lane = threadIdx.x & 63;
  int v = (lane < NB) ? bsums[w * NB + lane] : 0;
  int incl = v;
#pragma unroll
  for (int off = 1; off < 64; off <<= 1) {
    int t = __shfl_up(incl, off, 64);
    if (lane >= off) incl += t;
  }
  if (lane < NB) bsums[w * NB + lane] = incl - v;
  if (lane == NB - 1) (w ? rp2 : rp1)[N_NODES] = incl;
}

// 3c) local scan + chunk offset -> rowptr & cursor.  grid = 2*NB, block 256.
__global__ __launch_bounds__(256) void localscan_kernel(
    const int* __restrict__ h1, const int* __restrict__ h2,
    const int* __restrict__ bsums,
    int* __restrict__ rp1, int* __restrict__ rp2,
    int* __restrict__ cur1, int* __restrict__ cur2) {
  int g = blockIdx.x >= NB;
  int b = blockIdx.x - g * NB;
  const int4* hist4 = (const int4*)(g ? h2 : h1);
  int* rp = g ? rp2 : rp1;
  int* cur = g ? cur2 : cur1;
  int tid = threadIdx.x, lane = tid & 63, wid = tid >> 6;
  int i4 = b * 256 + tid;
  int4 q = make_int4(0, 0, 0, 0);
  if (i4 < N_NODES / 4) q = hist4[i4];
  int e1 = q.x, e2 = q.x + q.y, e3 = e2 + q.z, s = e3 + q.w;
  int incl = s;
#pragma unroll
  for (int off = 1; off < 64; off <<= 1) {
    int t = __shfl_up(incl, off, 64);
    if (lane >= off) incl += t;
  }
  int texcl = incl - s;
  __shared__ int ws[4], wo[4];
  if (lane == 63) ws[wid] = incl;
  __syncthreads();
  if (tid == 0) {
    int r = 0;
#pragma unroll
    for (int w = 0; w < 4; ++w) { wo[w] = r; r += ws[w]; }
  }
  __syncthreads();
  int off0 = bsums[blockIdx.x] + wo[wid] + texcl;
  if (i4 < N_NODES / 4) {
    int4 r4 = make_int4(off0, off0 + e1, off0 + e2, off0 + e3);
    ((int4*)rp)[i4] = r4;
    ((int4*)cur)[i4] = r4;
  }
}

// 4) CSR fill; packed (src u16 | w fp16) per slot
__global__ __launch_bounds__(256) void fill_kernel(
    const int* __restrict__ ei1, const float* __restrict__ w1,
    int* __restrict__ cur1, unsigned* __restrict__ ec1,
    const int* __restrict__ ei2, const float* __restrict__ w2,
    int* __restrict__ cur2, unsigned* __restrict__ ec2) {
  int e = blockIdx.x * 256 + threadIdx.x;
  if (e >= N_EDGES) return;
  {
    int s = ei1[e], d = ei1[N_EDGES + e];
    int slot = atomicAdd(&cur1[d], 1);
    ec1[slot] = (unsigned)s |
                ((unsigned)__half_as_ushort(__float2half(w1[e])) << 16);
  }
  {
    int s = ei2[e], d = ei2[N_EDGES + e];
    int slot = atomicAdd(&cur2[d], 1);
    ec2[slot] = (unsigned)s |
                ((unsigned)__half_as_ushort(__float2half(w2[e])) << 16);
  }
}

// 4b) weighted degree from CSR -> dis = rsqrt(1 + sum w)
__global__ __launch_bounds__(256) void degdis_kernel(
    const int* __restrict__ rp1, const unsigned* __restrict__ ec1,
    const int* __restrict__ rp2, const unsigned* __restrict__ ec2,
    float* __restrict__ dis1, float* __restrict__ dis2) {
  int i = blockIdx.x * 256 + threadIdx.x;
  if (i >= 2 * N_NODES) return;
  const int* rp;
  const unsigned* ec;
  float* dis;
  int node;
  if (i < N_NODES) { rp = rp1; ec = ec1; dis = dis1; node = i; }
  else { rp = rp2; ec = ec2; dis = dis2; node = i - N_NODES; }
  float s = 1.0f;
  int e0 = rp[node], e1 = rp[node + 1];
  for (int e = e0; e < e1; ++e) s += pk_w(ec[e]);
  dis[node] = rsqrtf(s);
}

// ---------------------------------------------------------------------------
// 5) MFMA GEMM: Y[r] = dis[r] * (Xsel[r] @ W), fp16 out.
//    Block 256 = 4 waves, 64 rows/block, wave = 16 rows x 128 cols.
//    W fragments staged in LDS in MFMA layout (ds_read_b128).
//    mfma_f32_16x16x32_f16: A lane: row=l&15, k=(l>>4)*8+j.
//    C/D: col=lane&15, row=(lane>>4)*4+reg  [verified m89/m91].
template <bool XF16>
__global__ __launch_bounds__(256) void gemm_mfma_kernel(
    const void* __restrict__ X0v, const void* __restrict__ X1v,
    const float* __restrict__ W,
    const float* __restrict__ dis1, const float* __restrict__ dis2,
    __half* __restrict__ Y) {
  __shared__ half8 wfrag[4][8][64];  // 32 KB
  int tid = threadIdx.x;
  for (int ent = tid; ent < 4 * 8 * 64; ent += 256) {
    int lane = ent & 63, nt = (ent >> 6) & 7, kk = ent >> 9;
    int kbase = kk * 32 + (lane >> 4) * 8;
    int n = nt * 16 + (lane & 15);
    half8 hv;
#pragma unroll
    for (int j = 0; j < 8; ++j) hv[j] = (_Float16)W[(kbase + j) * 128 + n];
    wfrag[kk][nt][lane] = hv;
  }
  __syncthreads();
  int wv = tid >> 6, lane = tid & 63;
  int row0 = blockIdx.x * 64 + wv * 16;
  int arow = row0 + (lane & 15);
  int ar = (arow < 2 * N_NODES) ? arow : 0;  // clamp (junk rows never stored)
  f32x4 acc[8] = {};
#pragma unroll
  for (int kk = 0; kk < 4; ++kk) {
    int kb = kk * 32 + (lane >> 4) * 8;
    half8 af;
    if constexpr (XF16) {
      const __half* xs = (ar < N_NODES)
                             ? ((const __half*)X0v + (size_t)ar * 128)
                             : ((const __half*)X1v + (size_t)(ar - N_NODES) * 128);
      af = *(const half8*)(xs + kb);
    } else {
      const float* xs = (ar < N_NODES)
                            ? ((const float*)X0v + (size_t)ar * 128)
                            : ((const float*)X1v + (size_t)(ar - N_NODES) * 128);
      float4 xa = *(const float4*)(xs + kb);
      float4 xb = *(const float4*)(xs + kb + 4);
      af[0] = (_Float16)xa.x; af[1] = (_Float16)xa.y;
      af[2] = (_Float16)xa.z; af[3] = (_Float16)xa.w;
      af[4] = (_Float16)xb.x; af[5] = (_Float16)xb.y;
      af[6] = (_Float16)xb.z; af[7] = (_Float16)xb.w;
    }
#pragma unroll
    for (int nt = 0; nt < 8; ++nt)
      acc[nt] = __builtin_amdgcn_mfma_f32_16x16x32_f16(af, wfrag[kk][nt][lane],
                                                       acc[nt], 0, 0, 0);
  }
#pragma unroll
  for (int rg = 0; rg < 4; ++rg) {
    int r = row0 + ((lane >> 4) * 4) + rg;
    if (r < 2 * N_NODES) {
      float d = (r < N_NODES) ? dis1[r] : dis2[r - N_NODES];
#pragma unroll
      for (int nt = 0; nt < 8; ++nt)
        Y[(size_t)r * 128 + nt * 16 + (lane & 15)] = __float2half(d * acc[nt][rg]);
    }
  }
}

// ---------------------------------------------------------------------------
// 6) layer-1 aggregate: out[idx] = b + dis*(H'[idx] + sum w_e H'[src])  (fp16 out)
//    4 nodes per wave (16-lane groups), idx in [0,2N).
__global__ __launch_bounds__(256) void aggregate1_kernel(
    const int* __restrict__ rp1, const unsigned* __restrict__ ec1,
    const float* __restrict__ dis1,
    const int* __restrict__ rp2, const unsigned* __restrict__ ec2,
    const float* __restrict__ dis2,
    const __half* __restrict__ H, const float* __restrict__ bias,
    __half* __restrict__ out) {
  int tid = threadIdx.x;
  int lane = tid & 63, grp = lane >> 4, fl = lane & 15;
  int idx = (blockIdx.x * 4 + (tid >> 6)) * 4 + grp;  // < 2N always (exact grid)
  const int* rp;
  const unsigned* ec;
  const float* dis;
  const float4* Hb4;
  int node;
  if (idx < N_NODES) {
    rp = rp1; ec = ec1; dis = dis1; node = idx;
    Hb4 = (const float4*)H;
  } else {
    rp = rp2; ec = ec2; dis = dis2; node = idx - N_NODES;
    Hb4 = (const float4*)(H + (size_t)N_NODES * 128);
  }
  float2 a[4];
  a[0] = a[1] = a[2] = a[3] = make_float2(0.f, 0.f);
  edge_gather_g16(ec, rp[node], rp[node + 1], Hb4, fl, a);
  float d = dis[node];
  float4 sraw = Hb4[(size_t)node * 16 + fl];
  const __half2* sp = (const __half2*)&sraw;
  __half2 o[4];
#pragma unroll
  for (int q = 0; q < 4; ++q) {
    float2 sv = __half22float2(sp[q]);
    float2 bz = *(const float2*)&bias[fl * 8 + q * 2];
    o[q] = __floats2half2_rn(bz.x + d * (sv.x + a[q].x),
                             bz.y + d * (sv.y + a[q].y));
  }
  *(float4*)&out[(size_t)idx * 128 + fl * 8] = *(float4*)o;
}

// 7) layer-2 aggregate + diff-product + pool.  4 nodes per wave.
__global__ __launch_bounds__(256) void aggregate2_pool_kernel(
    const int* __restrict__ rp1, const unsigned* __restrict__ ec1,
    const float* __restrict__ dis1,
    const int* __restrict__ rp2, const unsigned* __restrict__ ec2,
    const float* __restrict__ dis2,
    const __half* __restrict__ T,    // t1' at 0, t2' at N*128
    const __half* __restrict__ X1h,  // x11 at 0, x12 at N*128 (fp16)
    const float* __restrict__ b2, const int* __restrict__ batch,
    float* __restrict__ pool) {
  int tid = threadIdx.x;
  int lane = tid & 63, grp = lane >> 4, fl = lane & 15;
  int i = (blockIdx.x * 4 + (tid >> 6)) * 4 + grp;  // node < N (exact grid)
  const float4* T1 = (const float4*)T;
  const float4* T2 = (const float4*)(T + (size_t)N_NODES * 128);
  float2 a1[4], a2[4];
  a1[0] = a1[1] = a1[2] = a1[3] = make_float2(0.f, 0.f);
  a2[0] = a2[1] = a2[2] = a2[3] = make_float2(0.f, 0.f);
  edge_gather_g16(ec1, rp1[i], rp1[i + 1], T1, fl, a1);
  edge_gather_g16(ec2, rp2[i], rp2[i + 1], T2, fl, a2);
  float d1 = dis1[i], d2 = dis2[i];
  float4 s1raw = T1[(size_t)i * 16 + fl];
  float4 s2raw = T2[(size_t)i * 16 + fl];
  float4 xaraw = *(const float4*)&X1h[(size_t)i * 128 + fl * 8];
  float4 xbraw = *(const float4*)&X1h[(size_t)(N_NODES + i) * 128 + fl * 8];
  const __half2* s1p = (const __half2*)&s1raw;
  const __half2* s2p = (const __half2*)&s2raw;
  const __half2* xap = (const __half2*)&xaraw;
  const __half2* xbp = (const __half2*)&xbraw;
  float v[8];
#pragma unroll
  for (int q = 0; q < 4; ++q) {
    float2 sv1 = __half22float2(s1p[q]);
    float2 sv2 = __half22float2(s2p[q]);
    float2 xa = __half22float2(xap[q]);
    float2 xb = __half22float2(xbp[q]);
    float2 bz = *(const float2*)&b2[fl * 8 + q * 2];
    float x21x = bz.x + d1 * (sv1.x + a1[q].x);
    float x21y = bz.y + d1 * (sv1.y + a1[q].y);
    float x22x = bz.x + d2 * (sv2.x + a2[q].x);
    float x22y = bz.y + d2 * (sv2.y + a2[q].y);
    v[2 * q] = (xb.x - xa.x) * (x22x - x21x);
    v[2 * q + 1] = (xb.y - xa.y) * (x22y - x21y);
  }
  int g = batch[i];
  int o1 = __shfl_xor(g, 16, 64);
  int o2 = __shfl_xor(g, 32, 64);
  int o3 = __shfl_xor(g, 48, 64);
  bool uni = (g == o1) && (g == o2) && (g == o3);
  if (__all(uni)) {
#pragma unroll
    for (int q = 0; q < 8; ++q) {
      v[q] += __shfl_xor(v[q], 16, 64);
      v[q] += __shfl_xor(v[q], 32, 64);
    }
    if (grp == 0) {
#pragma unroll
      for (int q = 0; q < 8; ++q)
        atomicAdd(&pool[g * 128 + fl * 8 + q], v[q]);
    }
  } else {
#pragma unroll
    for (int q = 0; q < 8; ++q)
      atomicAdd(&pool[g * 128 + fl * 8 + q], v[q]);
  }
}

// 8) per-graph mean + 4-layer MLP.  One block per graph, 128 threads.
__global__ __launch_bounds__(128) void mlp_kernel(
    const float* __restrict__ pool, const int* __restrict__ batch,
    const float* __restrict__ M1w, const float* __restrict__ M1b,
    const float* __restrict__ M2w, const float* __restrict__ M2b,
    const float* __restrict__ M3w, const float* __restrict__ M3b,
    const float* __restrict__ M4w, const float* __restrict__ M4b,
    float* __restrict__ out) {
  __shared__ float gv[128], t1[128], t2[64], t3[32];
  const int g = blockIdx.x, j = threadIdx.x;
  int lo, hi;
  { int a = 0, b = N_NODES; while (a < b) { int m = (a + b) >> 1; if (batch[m] < g) a = m + 1; else b = m; } lo = a; }
  { int a = lo, b = N_NODES; while (a < b) { int m = (a + b) >> 1; if (batch[m] < g + 1) a = m + 1; else b = m; } hi = a; }
  float cnt = (float)(hi - lo);
  if (cnt < 1.f) cnt = 1.f;
  gv[j] = pool[g * 128 + j] / cnt;
  __syncthreads();
  float a = M1b[j];
  for (int k = 0; k < 128; ++k) a += gv[k] * M1w[k * 128 + j];
  t1[j] = a;
  __syncthreads();
  if (j < 64) {
    float b = M2b[j];
    for (int k = 0; k < 128; ++k) b += t1[k] * M2w[k * 64 + j];
    t2[j] = b;
  }
  __syncthreads();
  if (j < 32) {
    float c = M3b[j];
    for (int k = 0; k < 64; ++k) c += t2[k] * M3w[k * 32 + j];
    t3[j] = c;
  }
  __syncthreads();
  if (j == 0) {
    float o = M4b[0];
    for (int k = 0; k < 32; ++k) o += t3[k] * M4w[k];
    out[g] = o;
  }
}

// ---------------------------------------------------------------------------
extern "C" void kernel_launch(void* const* d_in, const int* in_sizes, int n_in,
                              void* d_out, int out_size, void* d_ws, size_t ws_size,
                              hipStream_t stream) {
  const int* ei1 = (const int*)d_in[0];
  const float* w1 = (const float*)d_in[1];
  const int* ei2 = (const int*)d_in[2];
  const float* w2 = (const float*)d_in[3];
  const float* fm0 = (const float*)d_in[4];
  const float* fm1 = (const float*)d_in[5];
  const int* batch = (const int*)d_in[6];
  const float* W1 = (const float*)d_in[7];
  const float* b1 = (const float*)d_in[8];
  const float* W2 = (const float*)d_in[9];
  const float* b2 = (const float*)d_in[10];
  const float* M1w = (const float*)d_in[11];
  const float* M1b = (const float*)d_in[12];
  const float* M2w = (const float*)d_in[13];
  const float* M2b = (const float*)d_in[14];
  const float* M3w = (const float*)d_in[15];
  const float* M3b = (const float*)d_in[16];
  const float* M4w = (const float*)d_in[17];
  const float* M4b = (const float*)d_in[18];

  // workspace layout (float-element offsets, 16-element aligned)
  size_t off = 0;
  auto alloc = [&](size_t n) { size_t r = off; off += (n + 15) & ~(size_t)15; return r; };
  size_t o_hist1 = alloc(N_NODES);
  size_t o_hist2 = alloc(N_NODES);
  size_t o_pool = alloc(NGRAPH * 128);
  size_t zero_elems = off;  // everything above gets zeroed
  size_t o_dis1 = alloc(N_NODES);
  size_t o_dis2 = alloc(N_NODES);
  size_t o_rp1 = alloc(N_NODES + 1);
  size_t o_rp2 = alloc(N_NODES + 1);
  size_t o_cur1 = alloc(N_NODES);
  size_t o_cur2 = alloc(N_NODES);
  size_t o_bsums = alloc(2 * NB);
  size_t o_ec1 = alloc(N_EDGES);                // u32 per edge
  size_t o_ec2 = alloc(N_EDGES);
  size_t o_h = alloc((size_t)N_NODES * 128);    // 2N*128 halves
  size_t o_x1 = alloc((size_t)N_NODES * 128);   // 2N*128 halves (fp16 now)
  if (ws_size < off * sizeof(float)) return;  // insufficient workspace

  float* fbase = (float*)d_ws;
  int* ibase = (int*)d_ws;
  int* hist1 = ibase + o_hist1;
  int* hist2 = ibase + o_hist2;
  float* pool = fbase + o_pool;
  float* dis1 = fbase + o_dis1;
  float* dis2 = fbase + o_dis2;
  int* rp1 = ibase + o_rp1;
  int* rp2 = ibase + o_rp2;
  int* cur1 = ibase + o_cur1;
  int* cur2 = ibase + o_cur2;
  int* bsums = ibase + o_bsums;
  unsigned* ec1 = (unsigned*)(fbase + o_ec1);
  unsigned* ec2 = (unsigned*)(fbase + o_ec2);
  __half* h = (__half*)(fbase + o_h);
  __half* x1h = (__half*)(fbase + o_x1);

  hipMemsetAsync(d_ws, 0, zero_elems * sizeof(float), stream);

  edge_hist_kernel<<<(N_EDGES + 255) / 256, 256, 0, stream>>>(
      ei1, ei2, hist1, hist2);
  blocksum_kernel<<<2 * NB, 256, 0, stream>>>(hist1, hist2, bsums);
  scanbsums_kernel<<<1, 128, 0, stream>>>(bsums, rp1, rp2);
  localscan_kernel<<<2 * NB, 256, 0, stream>>>(
      hist1, hist2, bsums, rp1, rp2, cur1, cur2);
  fill_kernel<<<(N_EDGES + 255) / 256, 256, 0, stream>>>(
      ei1, w1, cur1, ec1, ei2, w2, cur2, ec2);
  degdis_kernel<<<(2 * N_NODES + 255) / 256, 256, 0, stream>>>(
      rp1, ec1, rp2, ec2, dis1, dis2);
  // layer 1: h' = dis * ([fm0; fm1] @ W1)  (fp32 in, fp16 out, MFMA)
  gemm_mfma_kernel<false><<<(2 * N_NODES + 63) / 64, 256, 0, stream>>>(
      fm0, fm1, W1, dis1, dis2, h);
  aggregate1_kernel<<<2 * N_NODES / 16, 256, 0, stream>>>(
      rp1, ec1, dis1, rp2, ec2, dis2, h, b1, x1h);
  // layer 2: t' = dis * ([x11; x12] @ W2)  (fp16 in, fp16 out, MFMA)
  gemm_mfma_kernel<true><<<(2 * N_NODES + 63) / 64, 256, 0, stream>>>(
      x1h, x1h + (size_t)N_NODES * 128, W2, dis1, dis2, h);
  aggregate2_pool_kernel<<<N_NODES / 16, 256, 0, stream>>>(
      rp1, ec1, dis1, rp2, ec2, dis2, h, x1h, b2, batch, pool);
  mlp_kernel<<<NGRAPH, 128, 0, stream>>>(
      pool, batch, M1w, M1b, M2w, M2b, M3w, M3b, M4w, M4b, (float*)d_out);
}